// Round 1
// baseline (3157.095 us; speedup 1.0000x reference)
//
#include <hip/hip_runtime.h>
#include <math.h>

// Problem constants (from setup_inputs)
constexpr int BB = 2;
constexpr int LL = 1024;
constexpr int DM = 1024;     // model dim
constexpr int DI = 2048;     // inner dim
constexpr int NS = 16;       // state dim
constexpr int RR = 64;       // dt rank
constexpr int MROWS = BB * LL;  // 2048 tokens

#define DEV __device__ __forceinline__

DEV float sigmoidf_(float x) { return 1.f / (1.f + expf(-x)); }
DEV float siluf_(float x) { return x * sigmoidf_(x); }
DEV float softplusf_(float x) { return (x > 20.f) ? x : log1pf(expf(x)); }

// ---------------------------------------------------------------------------
// LayerNorm: one block per token; writes BOTH directions' outputs (different
// scale/bias). Reversal doesn't matter (per-token op).
// ---------------------------------------------------------------------------
__global__ __launch_bounds__(256) void ln_kernel(
    const float* __restrict__ x,      // [MROWS, DM]
    const float* __restrict__ ln_w,   // [2, DM]
    const float* __restrict__ ln_b,   // [2, DM]
    float* __restrict__ xln0,         // [MROWS, DM]
    float* __restrict__ xln1)         // [MROWS, DM]
{
    int row = blockIdx.x;
    const float* xr = x + (size_t)row * DM;
    float s = 0.f, s2 = 0.f;
    // 1024 floats, 256 threads -> 1 float4 each
    int i4 = threadIdx.x * 4;
    float4 v = *reinterpret_cast<const float4*>(&xr[i4]);
    s = v.x + v.y + v.z + v.w;
    s2 = v.x * v.x + v.y * v.y + v.z * v.z + v.w * v.w;
    // wave reduce
    for (int off = 32; off > 0; off >>= 1) {
        s += __shfl_down(s, off);
        s2 += __shfl_down(s2, off);
    }
    __shared__ float sbuf[10];
    int wid = threadIdx.x >> 6;
    if ((threadIdx.x & 63) == 0) { sbuf[wid] = s; sbuf[4 + wid] = s2; }
    __syncthreads();
    if (threadIdx.x == 0) {
        float S = sbuf[0] + sbuf[1] + sbuf[2] + sbuf[3];
        float S2 = sbuf[4] + sbuf[5] + sbuf[6] + sbuf[7];
        float mu = S / DM;
        float var = S2 / DM - mu * mu;
        sbuf[8] = mu;
        sbuf[9] = rsqrtf(var + 1e-5f);
    }
    __syncthreads();
    float mu = sbuf[8], rstd = sbuf[9];
    float4 w0 = *reinterpret_cast<const float4*>(&ln_w[i4]);
    float4 b0 = *reinterpret_cast<const float4*>(&ln_b[i4]);
    float4 w1 = *reinterpret_cast<const float4*>(&ln_w[DM + i4]);
    float4 b1 = *reinterpret_cast<const float4*>(&ln_b[DM + i4]);
    float4 nv;
    nv.x = (v.x - mu) * rstd; nv.y = (v.y - mu) * rstd;
    nv.z = (v.z - mu) * rstd; nv.w = (v.w - mu) * rstd;
    float4 o0, o1;
    o0.x = nv.x * w0.x + b0.x; o0.y = nv.y * w0.y + b0.y;
    o0.z = nv.z * w0.z + b0.z; o0.w = nv.w * w0.w + b0.w;
    o1.x = nv.x * w1.x + b1.x; o1.y = nv.y * w1.y + b1.y;
    o1.z = nv.z * w1.z + b1.z; o1.w = nv.w * w1.w + b1.w;
    *reinterpret_cast<float4*>(&xln0[(size_t)row * DM + i4]) = o0;
    *reinterpret_cast<float4*>(&xln1[(size_t)row * DM + i4]) = o1;
}

// ---------------------------------------------------------------------------
// Generic 64x64-tile fp32 GEMM: C = epilogue(A @ W + bias)
// A: [M,K] lda; W: [K,N] ldw; C: [M,N] ldc
// ---------------------------------------------------------------------------
enum { EPI_BIAS = 0, EPI_SOFTPLUS = 1, EPI_RES_BIAS = 2 };

template <int EPI>
__global__ __launch_bounds__(256) void gemm64(
    const float* __restrict__ A, int lda,
    const float* __restrict__ W, int ldw,
    const float* __restrict__ bias,
    float* __restrict__ C, int ldc,
    const float* __restrict__ res, int ldres,
    int Mdim, int Ndim, int Kdim)
{
    __shared__ float As[16][68];
    __shared__ float Bs[16][68];
    int tid = threadIdx.x;
    int tx = tid & 15, ty = tid >> 4;
    int row0 = blockIdx.y * 64;
    int col0 = blockIdx.x * 64;
    float acc[4][4] = {};

    for (int k0 = 0; k0 < Kdim; k0 += 16) {
#pragma unroll
        for (int j = 0; j < 4; ++j) {
            int r = (tid >> 4) + 16 * j;
            int kk = tid & 15;
            As[kk][r] = A[(size_t)(row0 + r) * lda + (k0 + kk)];
        }
#pragma unroll
        for (int j = 0; j < 4; ++j) {
            int kr = (tid >> 6) + 4 * j;
            int cc = tid & 63;
            int col = col0 + cc;
            Bs[kr][cc] = (col < Ndim) ? W[(size_t)(k0 + kr) * ldw + col] : 0.f;
        }
        __syncthreads();
#pragma unroll
        for (int k = 0; k < 16; ++k) {
            float4 av = *reinterpret_cast<const float4*>(&As[k][ty * 4]);
            float4 bv = *reinterpret_cast<const float4*>(&Bs[k][tx * 4]);
            float a[4] = {av.x, av.y, av.z, av.w};
            float b[4] = {bv.x, bv.y, bv.z, bv.w};
#pragma unroll
            for (int m = 0; m < 4; ++m)
#pragma unroll
                for (int n = 0; n < 4; ++n)
                    acc[m][n] = fmaf(a[m], b[n], acc[m][n]);
        }
        __syncthreads();
    }

#pragma unroll
    for (int m = 0; m < 4; ++m) {
        int row = row0 + ty * 4 + m;
#pragma unroll
        for (int n = 0; n < 4; ++n) {
            int col = col0 + tx * 4 + n;
            if (col >= Ndim) continue;
            float v = acc[m][n];
            if (bias) v += bias[col];
            if constexpr (EPI == EPI_SOFTPLUS) {
                v = softplusf_(v);
            } else if constexpr (EPI == EPI_RES_BIAS) {
                v += res[(size_t)row * ldres + col];
            }
            C[(size_t)row * ldc + col] = v;
        }
    }
}

// ---------------------------------------------------------------------------
// Depthwise causal (fwd) / anticausal (bwd) conv K=4 + SiLU.
// Input xp = xz[:, 0:DI] (row stride 2*DI); output xpc [MROWS, DI].
// ---------------------------------------------------------------------------
__global__ __launch_bounds__(256) void conv_silu_kernel(
    const float* __restrict__ xz,     // [MROWS, 2*DI]
    const float* __restrict__ cw,     // [DI, 4]
    const float* __restrict__ cb,     // [DI]
    float* __restrict__ xpc,          // [MROWS, DI]
    int reverse)
{
    int idx = blockIdx.x * 256 + threadIdx.x;  // over MROWS*DI
    int c = idx & (DI - 1);
    int row = idx >> 11;   // DI = 2048 = 2^11
    int t = row & (LL - 1);
    int b = row >> 10;     // LL = 1024 = 2^10
    float w0 = cw[c * 4 + 0], w1 = cw[c * 4 + 1], w2 = cw[c * 4 + 2], w3 = cw[c * 4 + 3];
    float acc = cb[c];
    if (!reverse) {
        // y[t] = sum_k w[k] * x[t-3+k]
#pragma unroll
        for (int k = 0; k < 4; ++k) {
            int tt = t - 3 + k;
            if (tt >= 0) {
                float wv = (k == 0) ? w0 : (k == 1) ? w1 : (k == 2) ? w2 : w3;
                acc = fmaf(wv, xz[(size_t)(b * LL + tt) * (2 * DI) + c], acc);
            }
        }
    } else {
        // y[t] = sum_k w[k] * x[t+3-k]
#pragma unroll
        for (int k = 0; k < 4; ++k) {
            int tt = t + 3 - k;
            if (tt < LL) {
                float wv = (k == 0) ? w0 : (k == 1) ? w1 : (k == 2) ? w2 : w3;
                acc = fmaf(wv, xz[(size_t)(b * LL + tt) * (2 * DI) + c], acc);
            }
        }
    }
    xpc[idx] = siluf_(acc);
}

// ---------------------------------------------------------------------------
// Fused selective scan + output gating.
// 16 lanes per channel (one per state n). Grid (DI/16, BB), 256 threads.
// ybuf[b,t,c] = (sum_n h_n*C_n + xpc*Dp[c]) * silu(z[b,t,c])
// ---------------------------------------------------------------------------
__global__ __launch_bounds__(256) void scan_kernel(
    const float* __restrict__ delta,  // [MROWS, DI]
    const float* __restrict__ xpc,    // [MROWS, DI]
    const float* __restrict__ dbl,    // [MROWS, 96] (dt|B|C)
    const float* __restrict__ xz,     // [MROWS, 2*DI] (z at col DI+c)
    const float* __restrict__ A_log,  // [DI, NS]
    const float* __restrict__ Dp,     // [DI]
    float* __restrict__ ybuf,         // [MROWS, DI]
    int reverse)
{
    int n = threadIdx.x & 15;
    int cg = threadIdx.x >> 4;            // 0..15
    int c = blockIdx.x * 16 + cg;
    int b = blockIdx.y;
    float Ac = -expf(A_log[c * NS + n]);
    float Dc = Dp[c];
    float h = 0.f;
    int base = b * LL;
    for (int i = 0; i < LL; ++i) {
        int t = reverse ? (LL - 1 - i) : i;
        size_t rowIdx = (size_t)(base + t);
        float dlt = delta[rowIdx * DI + c];
        float xv = xpc[rowIdx * DI + c];
        float Bv = dbl[rowIdx * 96 + RR + n];
        float Cv = dbl[rowIdx * 96 + RR + NS + n];
        float dA = expf(dlt * Ac);
        h = fmaf(dA, h, dlt * Bv * xv);
        float contrib = h * Cv;
        contrib += __shfl_xor(contrib, 8, 16);
        contrib += __shfl_xor(contrib, 4, 16);
        contrib += __shfl_xor(contrib, 2, 16);
        contrib += __shfl_xor(contrib, 1, 16);
        if (n == 0) {
            float z = xz[rowIdx * (2 * DI) + DI + c];
            ybuf[rowIdx * DI + c] = (contrib + xv * Dc) * siluf_(z);
        }
    }
}

// ---------------------------------------------------------------------------
// Final combine: gate = sigmoid(comb@Wg+bg), value = comb@Wv+bv
// out = 0.5*(gate*value + (1-gate)*(fwd+bwd))
// comb: [MROWS, 2*DM] with fwd in cols [0,DM), bwd in [DM, 2*DM)
// ---------------------------------------------------------------------------
__global__ __launch_bounds__(256) void gemm_combine(
    const float* __restrict__ A,   // comb [MROWS, 2*DM]
    const float* __restrict__ Wg, const float* __restrict__ bg,
    const float* __restrict__ Wv, const float* __restrict__ bv,
    float* __restrict__ out)       // [MROWS, DM]
{
    __shared__ float As[16][68];
    __shared__ float Bg[16][68];
    __shared__ float Bv[16][68];
    int tid = threadIdx.x;
    int tx = tid & 15, ty = tid >> 4;
    int row0 = blockIdx.y * 64;
    int col0 = blockIdx.x * 64;
    float accg[4][4] = {};
    float accv[4][4] = {};
    const int K = 2 * DM;   // 2048
    for (int k0 = 0; k0 < K; k0 += 16) {
#pragma unroll
        for (int j = 0; j < 4; ++j) {
            int r = (tid >> 4) + 16 * j;
            int kk = tid & 15;
            As[kk][r] = A[(size_t)(row0 + r) * (2 * DM) + (k0 + kk)];
        }
#pragma unroll
        for (int j = 0; j < 4; ++j) {
            int kr = (tid >> 6) + 4 * j;
            int cc = tid & 63;
            Bg[kr][cc] = Wg[(size_t)(k0 + kr) * DM + col0 + cc];
            Bv[kr][cc] = Wv[(size_t)(k0 + kr) * DM + col0 + cc];
        }
        __syncthreads();
#pragma unroll
        for (int k = 0; k < 16; ++k) {
            float4 av = *reinterpret_cast<const float4*>(&As[k][ty * 4]);
            float4 bgv = *reinterpret_cast<const float4*>(&Bg[k][tx * 4]);
            float4 bvv = *reinterpret_cast<const float4*>(&Bv[k][tx * 4]);
            float a[4] = {av.x, av.y, av.z, av.w};
            float g[4] = {bgv.x, bgv.y, bgv.z, bgv.w};
            float v[4] = {bvv.x, bvv.y, bvv.z, bvv.w};
#pragma unroll
            for (int m = 0; m < 4; ++m)
#pragma unroll
                for (int n = 0; n < 4; ++n) {
                    accg[m][n] = fmaf(a[m], g[n], accg[m][n]);
                    accv[m][n] = fmaf(a[m], v[n], accv[m][n]);
                }
        }
        __syncthreads();
    }
#pragma unroll
    for (int m = 0; m < 4; ++m) {
        int row = row0 + ty * 4 + m;
#pragma unroll
        for (int n = 0; n < 4; ++n) {
            int col = col0 + tx * 4 + n;
            float g = sigmoidf_(accg[m][n] + bg[col]);
            float v = accv[m][n] + bv[col];
            float f = A[(size_t)row * (2 * DM) + col];
            float w = A[(size_t)row * (2 * DM) + DM + col];
            out[(size_t)row * DM + col] = 0.5f * (g * v + (1.f - g) * (f + w));
        }
    }
}

// ---------------------------------------------------------------------------
extern "C" void kernel_launch(void* const* d_in, const int* in_sizes, int n_in,
                              void* d_out, int out_size, void* d_ws, size_t ws_size,
                              hipStream_t stream)
{
    const float* x      = (const float*)d_in[0];
    const float* ln_w   = (const float*)d_in[1];
    const float* ln_b   = (const float*)d_in[2];
    const float* W_in   = (const float*)d_in[3];
    const float* b_in   = (const float*)d_in[4];
    const float* conv_w = (const float*)d_in[5];
    const float* conv_b = (const float*)d_in[6];
    const float* W_xproj= (const float*)d_in[7];
    const float* W_dt   = (const float*)d_in[8];
    const float* b_dt   = (const float*)d_in[9];
    const float* A_log  = (const float*)d_in[10];
    const float* Dp     = (const float*)d_in[11];
    const float* W_out  = (const float*)d_in[12];
    const float* b_out  = (const float*)d_in[13];
    const float* Wg     = (const float*)d_in[14];
    const float* bg     = (const float*)d_in[15];
    const float* Wv     = (const float*)d_in[16];
    const float* bv     = (const float*)d_in[17];
    float* out = (float*)d_out;

    float* ws = (float*)d_ws;
    size_t off = 0;
    float* xln0  = ws + off; off += (size_t)MROWS * DM;       // 2M
    float* xln1  = ws + off; off += (size_t)MROWS * DM;       // 2M
    float* xz    = ws + off; off += (size_t)MROWS * 2 * DI;   // 8M
    float* xpc   = ws + off; off += (size_t)MROWS * DI;       // 4M
    float* dblb  = ws + off; off += (size_t)MROWS * 96;       // 0.19M
    float* delta = ws + off; off += (size_t)MROWS * DI;       // 4M
    float* ybuf  = ws + off; off += (size_t)MROWS * DI;       // 4M
    float* comb  = ws + off; off += (size_t)MROWS * 2 * DM;   // 4M

    // 1) LayerNorm (both directions)
    ln_kernel<<<MROWS, 256, 0, stream>>>(x, ln_w, ln_b, xln0, xln1);

    for (int d = 0; d < 2; ++d) {
        const float* xln = d ? xln1 : xln0;
        // 2) xz = xln @ W_in[d] + b_in[d]   [2048 x 4096], K=1024
        gemm64<EPI_BIAS><<<dim3(2 * DI / 64, MROWS / 64), 256, 0, stream>>>(
            xln, DM, W_in + (size_t)d * DM * 2 * DI, 2 * DI, b_in + (size_t)d * 2 * DI,
            xz, 2 * DI, nullptr, 0, MROWS, 2 * DI, DM);
        // 3) conv + silu -> xpc
        conv_silu_kernel<<<(MROWS * DI) / 256, 256, 0, stream>>>(
            xz, conv_w + (size_t)d * DI * 4, conv_b + (size_t)d * DI, xpc, d);
        // 4) dbl = xpc @ W_xproj[d]   [2048 x 96], K=2048
        gemm64<EPI_BIAS><<<dim3(2, MROWS / 64), 256, 0, stream>>>(
            xpc, DI, W_xproj + (size_t)d * DI * 96, 96, nullptr,
            dblb, 96, nullptr, 0, MROWS, 96, DI);
        // 5) delta = softplus(dbl[:, :64] @ W_dt[d] + b_dt[d])  [2048 x 2048], K=64
        gemm64<EPI_SOFTPLUS><<<dim3(DI / 64, MROWS / 64), 256, 0, stream>>>(
            dblb, 96, W_dt + (size_t)d * RR * DI, DI, b_dt + (size_t)d * DI,
            delta, DI, nullptr, 0, MROWS, DI, RR);
        // 6) fused scan + gating -> ybuf
        scan_kernel<<<dim3(DI / 16, BB), 256, 0, stream>>>(
            delta, xpc, dblb, xz, A_log + (size_t)d * DI * NS, Dp + (size_t)d * DI,
            ybuf, d);
        // 7) comb[:, d*DM:...] = x + ybuf @ W_out[d] + b_out[d]  [2048 x 1024], K=2048
        gemm64<EPI_RES_BIAS><<<dim3(DM / 64, MROWS / 64), 256, 0, stream>>>(
            ybuf, DI, W_out + (size_t)d * DI * DM, DM, b_out + (size_t)d * DM,
            comb + (size_t)d * DM, 2 * DM, x, DM, MROWS, DM, DI);
    }

    // 8) final combine
    gemm_combine<<<dim3(DM / 64, MROWS / 64), 256, 0, stream>>>(
        comb, Wg, bg, Wv, bv, out);
}

// Round 2
// 1636.135 us; speedup vs baseline: 1.9296x; 1.9296x over previous
//
#include <hip/hip_runtime.h>
#include <math.h>

// Problem constants (from setup_inputs)
constexpr int BB = 2;
constexpr int LL = 1024;
constexpr int DM = 1024;     // model dim
constexpr int DI = 2048;     // inner dim
constexpr int NS = 16;       // state dim
constexpr int RR = 64;       // dt rank
constexpr int MROWS = BB * LL;  // 2048 tokens

// chunked scan
constexpr int CLEN = 16;
constexpr int NCH = LL / CLEN;  // 64

#define DEV __device__ __forceinline__

DEV float sigmoidf_(float x) { return 1.f / (1.f + expf(-x)); }
DEV float siluf_(float x) { return x * sigmoidf_(x); }
DEV float softplusf_(float x) { return (x > 20.f) ? x : log1pf(expf(x)); }

// ---------------------------------------------------------------------------
// LayerNorm: one block per token; writes BOTH directions' outputs.
// ---------------------------------------------------------------------------
__global__ __launch_bounds__(256) void ln_kernel(
    const float* __restrict__ x,      // [MROWS, DM]
    const float* __restrict__ ln_w,   // [2, DM]
    const float* __restrict__ ln_b,   // [2, DM]
    float* __restrict__ xln0,         // [MROWS, DM]
    float* __restrict__ xln1)         // [MROWS, DM]
{
    int row = blockIdx.x;
    const float* xr = x + (size_t)row * DM;
    float s = 0.f, s2 = 0.f;
    int i4 = threadIdx.x * 4;
    float4 v = *reinterpret_cast<const float4*>(&xr[i4]);
    s = v.x + v.y + v.z + v.w;
    s2 = v.x * v.x + v.y * v.y + v.z * v.z + v.w * v.w;
    for (int off = 32; off > 0; off >>= 1) {
        s += __shfl_down(s, off);
        s2 += __shfl_down(s2, off);
    }
    __shared__ float sbuf[10];
    int wid = threadIdx.x >> 6;
    if ((threadIdx.x & 63) == 0) { sbuf[wid] = s; sbuf[4 + wid] = s2; }
    __syncthreads();
    if (threadIdx.x == 0) {
        float S = sbuf[0] + sbuf[1] + sbuf[2] + sbuf[3];
        float S2 = sbuf[4] + sbuf[5] + sbuf[6] + sbuf[7];
        float mu = S / DM;
        float var = S2 / DM - mu * mu;
        sbuf[8] = mu;
        sbuf[9] = rsqrtf(var + 1e-5f);
    }
    __syncthreads();
    float mu = sbuf[8], rstd = sbuf[9];
    float4 w0 = *reinterpret_cast<const float4*>(&ln_w[i4]);
    float4 b0 = *reinterpret_cast<const float4*>(&ln_b[i4]);
    float4 w1 = *reinterpret_cast<const float4*>(&ln_w[DM + i4]);
    float4 b1 = *reinterpret_cast<const float4*>(&ln_b[DM + i4]);
    float4 nv;
    nv.x = (v.x - mu) * rstd; nv.y = (v.y - mu) * rstd;
    nv.z = (v.z - mu) * rstd; nv.w = (v.w - mu) * rstd;
    float4 o0, o1;
    o0.x = nv.x * w0.x + b0.x; o0.y = nv.y * w0.y + b0.y;
    o0.z = nv.z * w0.z + b0.z; o0.w = nv.w * w0.w + b0.w;
    o1.x = nv.x * w1.x + b1.x; o1.y = nv.y * w1.y + b1.y;
    o1.z = nv.z * w1.z + b1.z; o1.w = nv.w * w1.w + b1.w;
    *reinterpret_cast<float4*>(&xln0[(size_t)row * DM + i4]) = o0;
    *reinterpret_cast<float4*>(&xln1[(size_t)row * DM + i4]) = o1;
}

// ---------------------------------------------------------------------------
// Generic 64x64-tile fp32 GEMM: C = epilogue(A @ W + bias)
// ---------------------------------------------------------------------------
enum { EPI_BIAS = 0, EPI_SOFTPLUS = 1, EPI_RES_BIAS = 2 };

template <int EPI>
__global__ __launch_bounds__(256) void gemm64(
    const float* __restrict__ A, int lda,
    const float* __restrict__ W, int ldw,
    const float* __restrict__ bias,
    float* __restrict__ C, int ldc,
    const float* __restrict__ res, int ldres,
    int Mdim, int Ndim, int Kdim)
{
    __shared__ float As[16][68];
    __shared__ float Bs[16][68];
    int tid = threadIdx.x;
    int tx = tid & 15, ty = tid >> 4;
    int row0 = blockIdx.y * 64;
    int col0 = blockIdx.x * 64;
    float acc[4][4] = {};

    for (int k0 = 0; k0 < Kdim; k0 += 16) {
#pragma unroll
        for (int j = 0; j < 4; ++j) {
            int r = (tid >> 4) + 16 * j;
            int kk = tid & 15;
            As[kk][r] = A[(size_t)(row0 + r) * lda + (k0 + kk)];
        }
#pragma unroll
        for (int j = 0; j < 4; ++j) {
            int kr = (tid >> 6) + 4 * j;
            int cc = tid & 63;
            int col = col0 + cc;
            Bs[kr][cc] = (col < Ndim) ? W[(size_t)(k0 + kr) * ldw + col] : 0.f;
        }
        __syncthreads();
#pragma unroll
        for (int k = 0; k < 16; ++k) {
            float4 av = *reinterpret_cast<const float4*>(&As[k][ty * 4]);
            float4 bv = *reinterpret_cast<const float4*>(&Bs[k][tx * 4]);
            float a[4] = {av.x, av.y, av.z, av.w};
            float b[4] = {bv.x, bv.y, bv.z, bv.w};
#pragma unroll
            for (int m = 0; m < 4; ++m)
#pragma unroll
                for (int n = 0; n < 4; ++n)
                    acc[m][n] = fmaf(a[m], b[n], acc[m][n]);
        }
        __syncthreads();
    }

#pragma unroll
    for (int m = 0; m < 4; ++m) {
        int row = row0 + ty * 4 + m;
#pragma unroll
        for (int n = 0; n < 4; ++n) {
            int col = col0 + tx * 4 + n;
            if (col >= Ndim) continue;
            float v = acc[m][n];
            if (bias) v += bias[col];
            if constexpr (EPI == EPI_SOFTPLUS) {
                v = softplusf_(v);
            } else if constexpr (EPI == EPI_RES_BIAS) {
                v += res[(size_t)row * ldres + col];
            }
            C[(size_t)row * ldc + col] = v;
        }
    }
}

// ---------------------------------------------------------------------------
// Depthwise causal (fwd) / anticausal (bwd) conv K=4 + SiLU.
// ---------------------------------------------------------------------------
__global__ __launch_bounds__(256) void conv_silu_kernel(
    const float* __restrict__ xz,     // [MROWS, 2*DI]
    const float* __restrict__ cw,     // [DI, 4]
    const float* __restrict__ cb,     // [DI]
    float* __restrict__ xpc,          // [MROWS, DI]
    int reverse)
{
    int idx = blockIdx.x * 256 + threadIdx.x;  // over MROWS*DI
    int c = idx & (DI - 1);
    int row = idx >> 11;   // DI = 2048 = 2^11
    int t = row & (LL - 1);
    int b = row >> 10;     // LL = 1024 = 2^10
    float w0 = cw[c * 4 + 0], w1 = cw[c * 4 + 1], w2 = cw[c * 4 + 2], w3 = cw[c * 4 + 3];
    float acc = cb[c];
    if (!reverse) {
#pragma unroll
        for (int k = 0; k < 4; ++k) {
            int tt = t - 3 + k;
            if (tt >= 0) {
                float wv = (k == 0) ? w0 : (k == 1) ? w1 : (k == 2) ? w2 : w3;
                acc = fmaf(wv, xz[(size_t)(b * LL + tt) * (2 * DI) + c], acc);
            }
        }
    } else {
#pragma unroll
        for (int k = 0; k < 4; ++k) {
            int tt = t + 3 - k;
            if (tt < LL) {
                float wv = (k == 0) ? w0 : (k == 1) ? w1 : (k == 2) ? w2 : w3;
                acc = fmaf(wv, xz[(size_t)(b * LL + tt) * (2 * DI) + c], acc);
            }
        }
    }
    xpc[idx] = siluf_(acc);
}

// ---------------------------------------------------------------------------
// Chunked parallel scan. Recurrence per (b,c,n): h_t = exp(dlt_t*Ac)*h + dlt_t*B_t*x_t
// Phase 1: per (b,c,chunk): local scan from h=0 over CLEN steps.
//   Summary: S = sum(dlt) (A-product = exp(Ac*S)), h_final[16].
// ---------------------------------------------------------------------------
__global__ __launch_bounds__(256) void scan_part1(
    const float* __restrict__ delta,  // [MROWS, DI]
    const float* __restrict__ xpc,    // [MROWS, DI]
    const float* __restrict__ dbl,    // [MROWS, 96]
    const float* __restrict__ A_log,  // [DI, NS]
    float* __restrict__ chunkS,       // [B, NCH, DI]
    float* __restrict__ chunkH,       // [B, NCH, DI, NS]
    int reverse)
{
    int c = blockIdx.x * 256 + threadIdx.x;
    int ch = blockIdx.y;
    int b = blockIdx.z;
    int base = b * LL;

    __shared__ float sB[CLEN][16];
    {
        int r = threadIdx.x >> 4;        // 0..15
        int col = threadIdx.x & 15;
        int i = ch * CLEN + r;
        int t = reverse ? (LL - 1 - i) : i;
        sB[r][col] = dbl[(size_t)(base + t) * 96 + RR + col];
    }
    __syncthreads();

    float Ac[NS];
#pragma unroll
    for (int q = 0; q < 4; ++q) {
        float4 a = *reinterpret_cast<const float4*>(&A_log[(size_t)c * NS + q * 4]);
        Ac[q * 4 + 0] = -__expf(a.x);
        Ac[q * 4 + 1] = -__expf(a.y);
        Ac[q * 4 + 2] = -__expf(a.z);
        Ac[q * 4 + 3] = -__expf(a.w);
    }
    float h[NS] = {};
    float S = 0.f;
#pragma unroll
    for (int ii = 0; ii < CLEN; ++ii) {
        int i = ch * CLEN + ii;
        int t = reverse ? (LL - 1 - i) : i;
        size_t row = (size_t)(base + t);
        float dlt = delta[row * DI + c];
        float xv = xpc[row * DI + c];
        S += dlt;
        float dx = dlt * xv;
        float4 B0 = *reinterpret_cast<const float4*>(&sB[ii][0]);
        float4 B1 = *reinterpret_cast<const float4*>(&sB[ii][4]);
        float4 B2 = *reinterpret_cast<const float4*>(&sB[ii][8]);
        float4 B3 = *reinterpret_cast<const float4*>(&sB[ii][12]);
        float Bv[NS] = {B0.x, B0.y, B0.z, B0.w, B1.x, B1.y, B1.z, B1.w,
                        B2.x, B2.y, B2.z, B2.w, B3.x, B3.y, B3.z, B3.w};
#pragma unroll
        for (int n = 0; n < NS; ++n)
            h[n] = fmaf(__expf(dlt * Ac[n]), h[n], dx * Bv[n]);
    }
    size_t sidx = ((size_t)(b * NCH + ch)) * DI + c;
    chunkS[sidx] = S;
    float* hp = chunkH + sidx * NS;
#pragma unroll
    for (int q = 0; q < 4; ++q) {
        float4 o = make_float4(h[q * 4 + 0], h[q * 4 + 1], h[q * 4 + 2], h[q * 4 + 3]);
        *reinterpret_cast<float4*>(&hp[q * 4]) = o;
    }
}

// Phase 2: propagate h_in across chunks, in-place on chunkH.
// After this kernel, chunkH[b,j,c,n] = h state at the START of chunk j.
__global__ __launch_bounds__(256) void scan_part2(
    float* __restrict__ chunkH,       // [B, NCH, DI, NS]
    const float* __restrict__ chunkS, // [B, NCH, DI]
    const float* __restrict__ A_log)  // [DI, NS]
{
    int idx = blockIdx.x * 256 + threadIdx.x;   // over B*DI*NS
    int n = idx & 15;
    int c = (idx >> 4) & (DI - 1);
    int b = idx >> 15;                           // DI*NS = 2^15
    float Ac = -__expf(A_log[(size_t)c * NS + n]);
    float cur = 0.f;
    for (int j = 0; j < NCH; ++j) {
        size_t sidx = ((size_t)(b * NCH + j)) * DI + c;
        float S = chunkS[sidx];
        float hf = chunkH[sidx * NS + n];
        float nxt = fmaf(__expf(Ac * S), cur, hf);
        chunkH[sidx * NS + n] = cur;
        cur = nxt;
    }
}

// Phase 3: re-scan each chunk from h_in, fused C-contraction + D skip + silu(z) gate.
__global__ __launch_bounds__(256) void scan_part3(
    const float* __restrict__ delta,  // [MROWS, DI]
    const float* __restrict__ xpc,    // [MROWS, DI]
    const float* __restrict__ dbl,    // [MROWS, 96]
    const float* __restrict__ xz,     // [MROWS, 2*DI] (z at DI+c)
    const float* __restrict__ A_log,  // [DI, NS]
    const float* __restrict__ Dp,     // [DI]
    const float* __restrict__ chunkH, // [B, NCH, DI, NS] = h_in
    float* __restrict__ ybuf,         // [MROWS, DI]
    int reverse)
{
    int c = blockIdx.x * 256 + threadIdx.x;
    int ch = blockIdx.y;
    int b = blockIdx.z;
    int base = b * LL;

    __shared__ float sBC[CLEN][32];
    for (int r = threadIdx.x >> 5; r < CLEN; r += 8) {
        int col = threadIdx.x & 31;
        int i = ch * CLEN + r;
        int t = reverse ? (LL - 1 - i) : i;
        sBC[r][col] = dbl[(size_t)(base + t) * 96 + RR + col];
    }
    __syncthreads();

    float Ac[NS];
#pragma unroll
    for (int q = 0; q < 4; ++q) {
        float4 a = *reinterpret_cast<const float4*>(&A_log[(size_t)c * NS + q * 4]);
        Ac[q * 4 + 0] = -__expf(a.x);
        Ac[q * 4 + 1] = -__expf(a.y);
        Ac[q * 4 + 2] = -__expf(a.z);
        Ac[q * 4 + 3] = -__expf(a.w);
    }
    size_t sidx = ((size_t)(b * NCH + ch)) * DI + c;
    const float* hp = chunkH + sidx * NS;
    float h[NS];
#pragma unroll
    for (int q = 0; q < 4; ++q) {
        float4 hv = *reinterpret_cast<const float4*>(&hp[q * 4]);
        h[q * 4 + 0] = hv.x; h[q * 4 + 1] = hv.y;
        h[q * 4 + 2] = hv.z; h[q * 4 + 3] = hv.w;
    }
    float Dc = Dp[c];
#pragma unroll
    for (int ii = 0; ii < CLEN; ++ii) {
        int i = ch * CLEN + ii;
        int t = reverse ? (LL - 1 - i) : i;
        size_t row = (size_t)(base + t);
        float dlt = delta[row * DI + c];
        float xv = xpc[row * DI + c];
        float dx = dlt * xv;
        float4 B0 = *reinterpret_cast<const float4*>(&sBC[ii][0]);
        float4 B1 = *reinterpret_cast<const float4*>(&sBC[ii][4]);
        float4 B2 = *reinterpret_cast<const float4*>(&sBC[ii][8]);
        float4 B3 = *reinterpret_cast<const float4*>(&sBC[ii][12]);
        float4 C0 = *reinterpret_cast<const float4*>(&sBC[ii][16]);
        float4 C1 = *reinterpret_cast<const float4*>(&sBC[ii][20]);
        float4 C2 = *reinterpret_cast<const float4*>(&sBC[ii][24]);
        float4 C3 = *reinterpret_cast<const float4*>(&sBC[ii][28]);
        float Bv[NS] = {B0.x, B0.y, B0.z, B0.w, B1.x, B1.y, B1.z, B1.w,
                        B2.x, B2.y, B2.z, B2.w, B3.x, B3.y, B3.z, B3.w};
        float Cv[NS] = {C0.x, C0.y, C0.z, C0.w, C1.x, C1.y, C1.z, C1.w,
                        C2.x, C2.y, C2.z, C2.w, C3.x, C3.y, C3.z, C3.w};
        float y = 0.f;
#pragma unroll
        for (int n = 0; n < NS; ++n) {
            h[n] = fmaf(__expf(dlt * Ac[n]), h[n], dx * Bv[n]);
            y = fmaf(h[n], Cv[n], y);
        }
        float z = xz[row * (2 * DI) + DI + c];
        ybuf[row * DI + c] = (y + xv * Dc) * siluf_(z);
    }
}

// ---------------------------------------------------------------------------
// Final combine: gate = sigmoid(comb@Wg+bg), value = comb@Wv+bv
// ---------------------------------------------------------------------------
__global__ __launch_bounds__(256) void gemm_combine(
    const float* __restrict__ A,   // comb [MROWS, 2*DM]
    const float* __restrict__ Wg, const float* __restrict__ bg,
    const float* __restrict__ Wv, const float* __restrict__ bv,
    float* __restrict__ out)       // [MROWS, DM]
{
    __shared__ float As[16][68];
    __shared__ float Bg[16][68];
    __shared__ float Bv[16][68];
    int tid = threadIdx.x;
    int tx = tid & 15, ty = tid >> 4;
    int row0 = blockIdx.y * 64;
    int col0 = blockIdx.x * 64;
    float accg[4][4] = {};
    float accv[4][4] = {};
    const int K = 2 * DM;
    for (int k0 = 0; k0 < K; k0 += 16) {
#pragma unroll
        for (int j = 0; j < 4; ++j) {
            int r = (tid >> 4) + 16 * j;
            int kk = tid & 15;
            As[kk][r] = A[(size_t)(row0 + r) * (2 * DM) + (k0 + kk)];
        }
#pragma unroll
        for (int j = 0; j < 4; ++j) {
            int kr = (tid >> 6) + 4 * j;
            int cc = tid & 63;
            Bg[kr][cc] = Wg[(size_t)(k0 + kr) * DM + col0 + cc];
            Bv[kr][cc] = Wv[(size_t)(k0 + kr) * DM + col0 + cc];
        }
        __syncthreads();
#pragma unroll
        for (int k = 0; k < 16; ++k) {
            float4 av = *reinterpret_cast<const float4*>(&As[k][ty * 4]);
            float4 bgv = *reinterpret_cast<const float4*>(&Bg[k][tx * 4]);
            float4 bvv = *reinterpret_cast<const float4*>(&Bv[k][tx * 4]);
            float a[4] = {av.x, av.y, av.z, av.w};
            float g[4] = {bgv.x, bgv.y, bgv.z, bgv.w};
            float v[4] = {bvv.x, bvv.y, bvv.z, bvv.w};
#pragma unroll
            for (int m = 0; m < 4; ++m)
#pragma unroll
                for (int n = 0; n < 4; ++n) {
                    accg[m][n] = fmaf(a[m], g[n], accg[m][n]);
                    accv[m][n] = fmaf(a[m], v[n], accv[m][n]);
                }
        }
        __syncthreads();
    }
#pragma unroll
    for (int m = 0; m < 4; ++m) {
        int row = row0 + ty * 4 + m;
#pragma unroll
        for (int n = 0; n < 4; ++n) {
            int col = col0 + tx * 4 + n;
            float g = sigmoidf_(accg[m][n] + bg[col]);
            float v = accv[m][n] + bv[col];
            float f = A[(size_t)row * (2 * DM) + col];
            float w = A[(size_t)row * (2 * DM) + DM + col];
            out[(size_t)row * DM + col] = 0.5f * (g * v + (1.f - g) * (f + w));
        }
    }
}

// ---------------------------------------------------------------------------
extern "C" void kernel_launch(void* const* d_in, const int* in_sizes, int n_in,
                              void* d_out, int out_size, void* d_ws, size_t ws_size,
                              hipStream_t stream)
{
    const float* x      = (const float*)d_in[0];
    const float* ln_w   = (const float*)d_in[1];
    const float* ln_b   = (const float*)d_in[2];
    const float* W_in   = (const float*)d_in[3];
    const float* b_in   = (const float*)d_in[4];
    const float* conv_w = (const float*)d_in[5];
    const float* conv_b = (const float*)d_in[6];
    const float* W_xproj= (const float*)d_in[7];
    const float* W_dt   = (const float*)d_in[8];
    const float* b_dt   = (const float*)d_in[9];
    const float* A_log  = (const float*)d_in[10];
    const float* Dp     = (const float*)d_in[11];
    const float* W_out  = (const float*)d_in[12];
    const float* b_out  = (const float*)d_in[13];
    const float* Wg     = (const float*)d_in[14];
    const float* bg     = (const float*)d_in[15];
    const float* Wv     = (const float*)d_in[16];
    const float* bv     = (const float*)d_in[17];
    float* out = (float*)d_out;

    float* ws = (float*)d_ws;
    size_t off = 0;
    float* xln0  = ws + off; off += (size_t)MROWS * DM;        // 2M
    float* xln1  = ws + off; off += (size_t)MROWS * DM;        // 2M
    float* xz    = ws + off; off += (size_t)MROWS * 2 * DI;    // 8M
    float* xpc   = ws + off; off += (size_t)MROWS * DI;        // 4M
    float* dblb  = ws + off; off += (size_t)MROWS * 96;        // 0.19M
    float* delta = ws + off; off += (size_t)MROWS * DI;        // 4M
    float* ybuf  = ws + off; off += (size_t)MROWS * DI;        // 4M
    float* comb  = ws + off; off += (size_t)MROWS * 2 * DM;    // 4M
    float* chS   = ws + off; off += (size_t)BB * NCH * DI;     // 0.25M
    float* chH   = ws + off; off += (size_t)BB * NCH * DI * NS;// 4M

    // 1) LayerNorm (both directions)
    ln_kernel<<<MROWS, 256, 0, stream>>>(x, ln_w, ln_b, xln0, xln1);

    for (int d = 0; d < 2; ++d) {
        const float* xln = d ? xln1 : xln0;
        const float* Alg = A_log + (size_t)d * DI * NS;
        // 2) xz = xln @ W_in[d] + b_in[d]   [2048 x 4096], K=1024
        gemm64<EPI_BIAS><<<dim3(2 * DI / 64, MROWS / 64), 256, 0, stream>>>(
            xln, DM, W_in + (size_t)d * DM * 2 * DI, 2 * DI, b_in + (size_t)d * 2 * DI,
            xz, 2 * DI, nullptr, 0, MROWS, 2 * DI, DM);
        // 3) conv + silu -> xpc
        conv_silu_kernel<<<(MROWS * DI) / 256, 256, 0, stream>>>(
            xz, conv_w + (size_t)d * DI * 4, conv_b + (size_t)d * DI, xpc, d);
        // 4) dbl = xpc @ W_xproj[d]   [2048 x 96], K=2048
        gemm64<EPI_BIAS><<<dim3(2, MROWS / 64), 256, 0, stream>>>(
            xpc, DI, W_xproj + (size_t)d * DI * 96, 96, nullptr,
            dblb, 96, nullptr, 0, MROWS, 96, DI);
        // 5) delta = softplus(dbl[:, :64] @ W_dt[d] + b_dt[d])  [2048 x 2048], K=64
        gemm64<EPI_SOFTPLUS><<<dim3(DI / 64, MROWS / 64), 256, 0, stream>>>(
            dblb, 96, W_dt + (size_t)d * RR * DI, DI, b_dt + (size_t)d * DI,
            delta, DI, nullptr, 0, MROWS, DI, RR);
        // 6) chunked scan (3 phases) -> ybuf
        scan_part1<<<dim3(DI / 256, NCH, BB), 256, 0, stream>>>(
            delta, xpc, dblb, Alg, chS, chH, d);
        scan_part2<<<(BB * DI * NS) / 256, 256, 0, stream>>>(chH, chS, Alg);
        scan_part3<<<dim3(DI / 256, NCH, BB), 256, 0, stream>>>(
            delta, xpc, dblb, xz, Alg, Dp + (size_t)d * DI, chH, ybuf, d);
        // 7) comb[:, d*DM:...] = x + ybuf @ W_out[d] + b_out[d]  [2048 x 1024], K=2048
        gemm64<EPI_RES_BIAS><<<dim3(DM / 64, MROWS / 64), 256, 0, stream>>>(
            ybuf, DI, W_out + (size_t)d * DI * DM, DM, b_out + (size_t)d * DM,
            comb + (size_t)d * DM, 2 * DM, x, DM, MROWS, DM, DI);
    }

    // 8) final combine
    gemm_combine<<<dim3(DM / 64, MROWS / 64), 256, 0, stream>>>(
        comb, Wg, bg, Wv, bv, out);
}

// Round 3
// 832.926 us; speedup vs baseline: 3.7904x; 1.9643x over previous
//
#include <hip/hip_runtime.h>
#include <math.h>

constexpr int BB = 2;
constexpr int LL = 1024;
constexpr int DM = 1024;
constexpr int DI = 2048;
constexpr int NS = 16;
constexpr int RR = 64;
constexpr int MROWS = BB * LL;

constexpr int CLEN = 16;
constexpr int NCH = LL / CLEN;  // 64

constexpr int LDT = 40;         // LDS row stride (shorts) for 32-k tiles + pad

#define DEV __device__ __forceinline__

typedef unsigned short ushort_t;
using bf16x8 = __attribute__((ext_vector_type(8))) short;
using f32x4  = __attribute__((ext_vector_type(4))) float;

DEV float sigmoidf_(float x) { return 1.f / (1.f + expf(-x)); }
DEV float siluf_(float x) { return x * sigmoidf_(x); }
DEV float softplusf_(float x) { return (x > 20.f) ? x : log1pf(expf(x)); }

DEV ushort_t f2bf(float x) {
    union { float f; unsigned u; } v; v.f = x;
    unsigned r = v.u + 0x7FFFu + ((v.u >> 16) & 1u);
    return (ushort_t)(r >> 16);
}
DEV float bf2f(ushort_t u) {
    union { unsigned u; float f; } v; v.u = ((unsigned)u) << 16;
    return v.f;
}
DEV int4 cvt8(float4 a, float4 b) {
    ushort_t o[8] = {f2bf(a.x), f2bf(a.y), f2bf(a.z), f2bf(a.w),
                     f2bf(b.x), f2bf(b.y), f2bf(b.z), f2bf(b.w)};
    return *reinterpret_cast<int4*>(o);
}

// ---------------------------------------------------------------------------
// Transpose-cast: in fp32 [R][C] -> out bf16 [C][R]. 64x64 tiles.
// ---------------------------------------------------------------------------
__global__ __launch_bounds__(256) void tcast(
    const float* __restrict__ in, long sIn,
    ushort_t* __restrict__ outT, long sOut,
    int R, int C)
{
    in += (size_t)blockIdx.z * sIn;
    outT += (size_t)blockIdx.z * sOut;
    __shared__ float tile[64][65];
    int r0 = blockIdx.y * 64, c0 = blockIdx.x * 64;
#pragma unroll
    for (int i = 0; i < 4; ++i) {
        int r = (threadIdx.x >> 4) + i * 16;
        int c4 = (threadIdx.x & 15) * 4;
        float4 v = *reinterpret_cast<const float4*>(&in[(size_t)(r0 + r) * C + c0 + c4]);
        tile[r][c4] = v.x; tile[r][c4 + 1] = v.y; tile[r][c4 + 2] = v.z; tile[r][c4 + 3] = v.w;
    }
    __syncthreads();
#pragma unroll
    for (int i = 0; i < 2; ++i) {
        int c = (threadIdx.x >> 3) + i * 32;
        int r8 = (threadIdx.x & 7) * 8;
        ushort_t o[8];
#pragma unroll
        for (int j = 0; j < 8; ++j) o[j] = f2bf(tile[r8 + j][c]);
        *reinterpret_cast<int4*>(&outT[(size_t)(c0 + c) * R + r0 + r8]) =
            *reinterpret_cast<int4*>(o);
    }
}

// ---------------------------------------------------------------------------
// LayerNorm (one direction) -> bf16 output
// ---------------------------------------------------------------------------
__global__ __launch_bounds__(256) void ln_kernel(
    const float* __restrict__ x,
    const float* __restrict__ ln_w,
    const float* __restrict__ ln_b,
    ushort_t* __restrict__ xlnb)
{
    int row = blockIdx.x;
    const float* xr = x + (size_t)row * DM;
    int i4 = threadIdx.x * 4;
    float4 v = *reinterpret_cast<const float4*>(&xr[i4]);
    float s = v.x + v.y + v.z + v.w;
    float s2 = v.x * v.x + v.y * v.y + v.z * v.z + v.w * v.w;
    for (int off = 32; off > 0; off >>= 1) {
        s += __shfl_down(s, off);
        s2 += __shfl_down(s2, off);
    }
    __shared__ float sbuf[10];
    int wid = threadIdx.x >> 6;
    if ((threadIdx.x & 63) == 0) { sbuf[wid] = s; sbuf[4 + wid] = s2; }
    __syncthreads();
    if (threadIdx.x == 0) {
        float S = sbuf[0] + sbuf[1] + sbuf[2] + sbuf[3];
        float S2 = sbuf[4] + sbuf[5] + sbuf[6] + sbuf[7];
        float mu = S / DM;
        float var = S2 / DM - mu * mu;
        sbuf[8] = mu;
        sbuf[9] = rsqrtf(var + 1e-5f);
    }
    __syncthreads();
    float mu = sbuf[8], rstd = sbuf[9];
    float4 w = *reinterpret_cast<const float4*>(&ln_w[i4]);
    float4 b = *reinterpret_cast<const float4*>(&ln_b[i4]);
    ushort_t o[4];
    o[0] = f2bf((v.x - mu) * rstd * w.x + b.x);
    o[1] = f2bf((v.y - mu) * rstd * w.y + b.y);
    o[2] = f2bf((v.z - mu) * rstd * w.z + b.z);
    o[3] = f2bf((v.w - mu) * rstd * w.w + b.w);
    *reinterpret_cast<uint2*>(&xlnb[(size_t)row * DM + i4]) = *reinterpret_cast<uint2*>(o);
}

// ---------------------------------------------------------------------------
// bf16 MFMA GEMM, 128x128 tile, 4 waves (2x2), BK=32.
// A [M][K] bf16, Bt [N][K] bf16 (pre-transposed weights).
// EPI_XPZ: out = acc+bias; cols<DI -> fp32 xp; cols>=DI -> bf16 zb
// EPI_COMB: out fp32 = acc+bias+res
// ---------------------------------------------------------------------------
enum { EPI_XPZ = 0, EPI_COMB = 1 };

template <int EPI>
__global__ __launch_bounds__(256) void gemm_bf(
    const ushort_t* __restrict__ A, int lda,
    const ushort_t* __restrict__ Bt, int ldb,
    const float* __restrict__ bias,
    float* __restrict__ outF, int ldof,
    ushort_t* __restrict__ outB, int ldob,
    const float* __restrict__ res, int ldres,
    int Kdim)
{
    __shared__ ushort_t As[128 * LDT];
    __shared__ ushort_t Bs[128 * LDT];
    int tid = threadIdx.x;
    int lane = tid & 63;
    int w = tid >> 6, wr = w >> 1, wc = w & 1;
    int lrow = lane & 15, lk = lane >> 4;
    int row0 = blockIdx.y * 128, col0 = blockIdx.x * 128;

    f32x4 acc[4][4];
#pragma unroll
    for (int m = 0; m < 4; ++m)
#pragma unroll
        for (int n = 0; n < 4; ++n) acc[m][n] = {0.f, 0.f, 0.f, 0.f};

    int sr = tid >> 2, ss = tid & 3;
    const ushort_t* ga0 = A + (size_t)(row0 + sr) * lda + ss * 8;
    const ushort_t* ga1 = A + (size_t)(row0 + sr + 64) * lda + ss * 8;
    const ushort_t* gb0 = Bt + (size_t)(col0 + sr) * ldb + ss * 8;
    const ushort_t* gb1 = Bt + (size_t)(col0 + sr + 64) * ldb + ss * 8;

    for (int k0 = 0; k0 < Kdim; k0 += 32) {
        int4 a0 = *reinterpret_cast<const int4*>(ga0);
        int4 a1 = *reinterpret_cast<const int4*>(ga1);
        int4 b0 = *reinterpret_cast<const int4*>(gb0);
        int4 b1 = *reinterpret_cast<const int4*>(gb1);
        ga0 += 32; ga1 += 32; gb0 += 32; gb1 += 32;
        __syncthreads();
        *reinterpret_cast<int4*>(&As[sr * LDT + ss * 8]) = a0;
        *reinterpret_cast<int4*>(&As[(sr + 64) * LDT + ss * 8]) = a1;
        *reinterpret_cast<int4*>(&Bs[sr * LDT + ss * 8]) = b0;
        *reinterpret_cast<int4*>(&Bs[(sr + 64) * LDT + ss * 8]) = b1;
        __syncthreads();
        bf16x8 af[4], bfr[4];
#pragma unroll
        for (int m = 0; m < 4; ++m)
            af[m] = *reinterpret_cast<const bf16x8*>(&As[(wr * 64 + m * 16 + lrow) * LDT + lk * 8]);
#pragma unroll
        for (int n = 0; n < 4; ++n)
            bfr[n] = *reinterpret_cast<const bf16x8*>(&Bs[(wc * 64 + n * 16 + lrow) * LDT + lk * 8]);
#pragma unroll
        for (int m = 0; m < 4; ++m)
#pragma unroll
            for (int n = 0; n < 4; ++n)
                acc[m][n] = __builtin_amdgcn_mfma_f32_16x16x32_bf16(af[m], bfr[n], acc[m][n], 0, 0, 0);
    }

#pragma unroll
    for (int n = 0; n < 4; ++n) {
        int col = col0 + wc * 64 + n * 16 + lrow;
        float bv = bias[col];
#pragma unroll
        for (int m = 0; m < 4; ++m) {
#pragma unroll
            for (int rr = 0; rr < 4; ++rr) {
                int row = row0 + wr * 64 + m * 16 + lk * 4 + rr;
                float v = acc[m][n][rr] + bv;
                if constexpr (EPI == EPI_XPZ) {
                    if (col < DI) outF[(size_t)row * ldof + col] = v;
                    else outB[(size_t)row * ldob + (col - DI)] = f2bf(v);
                } else {
                    v += res[(size_t)row * ldres + col];
                    outF[(size_t)row * ldof + col] = v;
                }
            }
        }
    }
}

// ---------------------------------------------------------------------------
// Final fused GEMM: dual-B (Wg, Wv), A = comb fp32 (cast during staging),
// epilogue computes out = 0.5*(sig(g)*v + (1-sig(g))*(f+w)).
// ---------------------------------------------------------------------------
__global__ __launch_bounds__(256) void gemm_final(
    const float* __restrict__ comb, int lda,       // [M][2*DM]
    const ushort_t* __restrict__ Bg, const ushort_t* __restrict__ Bv, int ldb,
    const float* __restrict__ bg, const float* __restrict__ bvp,
    float* __restrict__ out)
{
    __shared__ ushort_t As[128 * LDT];
    __shared__ ushort_t Bs1[128 * LDT];
    __shared__ ushort_t Bs2[128 * LDT];
    int tid = threadIdx.x;
    int lane = tid & 63;
    int w = tid >> 6, wr = w >> 1, wc = w & 1;
    int lrow = lane & 15, lk = lane >> 4;
    int row0 = blockIdx.y * 128, col0 = blockIdx.x * 128;

    f32x4 accg[4][4], accv[4][4];
#pragma unroll
    for (int m = 0; m < 4; ++m)
#pragma unroll
        for (int n = 0; n < 4; ++n) { accg[m][n] = {0.f,0.f,0.f,0.f}; accv[m][n] = {0.f,0.f,0.f,0.f}; }

    int sr = tid >> 2, ss = tid & 3;
    const float* gaf0 = comb + (size_t)(row0 + sr) * lda + ss * 8;
    const float* gaf1 = comb + (size_t)(row0 + sr + 64) * lda + ss * 8;
    const ushort_t* gb0 = Bg + (size_t)(col0 + sr) * ldb + ss * 8;
    const ushort_t* gb1 = Bg + (size_t)(col0 + sr + 64) * ldb + ss * 8;
    const ushort_t* gc0 = Bv + (size_t)(col0 + sr) * ldb + ss * 8;
    const ushort_t* gc1 = Bv + (size_t)(col0 + sr + 64) * ldb + ss * 8;

    for (int k0 = 0; k0 < 2 * DM; k0 += 32) {
        float4 a00 = *reinterpret_cast<const float4*>(gaf0);
        float4 a01 = *reinterpret_cast<const float4*>(gaf0 + 4);
        float4 a10 = *reinterpret_cast<const float4*>(gaf1);
        float4 a11 = *reinterpret_cast<const float4*>(gaf1 + 4);
        int4 b0 = *reinterpret_cast<const int4*>(gb0);
        int4 b1 = *reinterpret_cast<const int4*>(gb1);
        int4 c0 = *reinterpret_cast<const int4*>(gc0);
        int4 c1 = *reinterpret_cast<const int4*>(gc1);
        gaf0 += 32; gaf1 += 32; gb0 += 32; gb1 += 32; gc0 += 32; gc1 += 32;
        int4 pa0 = cvt8(a00, a01);
        int4 pa1 = cvt8(a10, a11);
        __syncthreads();
        *reinterpret_cast<int4*>(&As[sr * LDT + ss * 8]) = pa0;
        *reinterpret_cast<int4*>(&As[(sr + 64) * LDT + ss * 8]) = pa1;
        *reinterpret_cast<int4*>(&Bs1[sr * LDT + ss * 8]) = b0;
        *reinterpret_cast<int4*>(&Bs1[(sr + 64) * LDT + ss * 8]) = b1;
        *reinterpret_cast<int4*>(&Bs2[sr * LDT + ss * 8]) = c0;
        *reinterpret_cast<int4*>(&Bs2[(sr + 64) * LDT + ss * 8]) = c1;
        __syncthreads();
        bf16x8 af[4], bf1[4], bf2[4];
#pragma unroll
        for (int m = 0; m < 4; ++m)
            af[m] = *reinterpret_cast<const bf16x8*>(&As[(wr * 64 + m * 16 + lrow) * LDT + lk * 8]);
#pragma unroll
        for (int n = 0; n < 4; ++n) {
            bf1[n] = *reinterpret_cast<const bf16x8*>(&Bs1[(wc * 64 + n * 16 + lrow) * LDT + lk * 8]);
            bf2[n] = *reinterpret_cast<const bf16x8*>(&Bs2[(wc * 64 + n * 16 + lrow) * LDT + lk * 8]);
        }
#pragma unroll
        for (int m = 0; m < 4; ++m)
#pragma unroll
            for (int n = 0; n < 4; ++n) {
                accg[m][n] = __builtin_amdgcn_mfma_f32_16x16x32_bf16(af[m], bf1[n], accg[m][n], 0, 0, 0);
                accv[m][n] = __builtin_amdgcn_mfma_f32_16x16x32_bf16(af[m], bf2[n], accv[m][n], 0, 0, 0);
            }
    }

#pragma unroll
    for (int n = 0; n < 4; ++n) {
        int col = col0 + wc * 64 + n * 16 + lrow;
        float bgv = bg[col];
        float bvv = bvp[col];
#pragma unroll
        for (int m = 0; m < 4; ++m) {
#pragma unroll
            for (int rr = 0; rr < 4; ++rr) {
                int row = row0 + wr * 64 + m * 16 + lk * 4 + rr;
                float g = sigmoidf_(accg[m][n][rr] + bgv);
                float v = accv[m][n][rr] + bvv;
                float f = comb[(size_t)row * lda + col];
                float wv2 = comb[(size_t)row * lda + DM + col];
                out[(size_t)row * DM + col] = 0.5f * (g * v + (1.f - g) * (f + wv2));
            }
        }
    }
}

// ---------------------------------------------------------------------------
// fp32 GEMM (small shapes: xproj, W_dt)
// ---------------------------------------------------------------------------
enum { EPI_BIAS = 0, EPI_SOFT_BF16 = 1 };

template <int EPI>
__global__ __launch_bounds__(256) void gemm64(
    const float* __restrict__ A, int lda,
    const float* __restrict__ W, int ldw,
    const float* __restrict__ bias,
    float* __restrict__ C, int ldc,
    int Ndim, int Kdim)
{
    __shared__ float As[16][68];
    __shared__ float Bs[16][68];
    int tid = threadIdx.x;
    int tx = tid & 15, ty = tid >> 4;
    int row0 = blockIdx.y * 64;
    int col0 = blockIdx.x * 64;
    float acc[4][4] = {};

    for (int k0 = 0; k0 < Kdim; k0 += 16) {
#pragma unroll
        for (int j = 0; j < 4; ++j) {
            int r = (tid >> 4) + 16 * j;
            int kk = tid & 15;
            As[kk][r] = A[(size_t)(row0 + r) * lda + (k0 + kk)];
        }
#pragma unroll
        for (int j = 0; j < 4; ++j) {
            int kr = (tid >> 6) + 4 * j;
            int cc = tid & 63;
            int col = col0 + cc;
            Bs[kr][cc] = (col < Ndim) ? W[(size_t)(k0 + kr) * ldw + col] : 0.f;
        }
        __syncthreads();
#pragma unroll
        for (int k = 0; k < 16; ++k) {
            float4 av = *reinterpret_cast<const float4*>(&As[k][ty * 4]);
            float4 bv = *reinterpret_cast<const float4*>(&Bs[k][tx * 4]);
            float a[4] = {av.x, av.y, av.z, av.w};
            float b[4] = {bv.x, bv.y, bv.z, bv.w};
#pragma unroll
            for (int m = 0; m < 4; ++m)
#pragma unroll
                for (int n = 0; n < 4; ++n)
                    acc[m][n] = fmaf(a[m], b[n], acc[m][n]);
        }
        __syncthreads();
    }

#pragma unroll
    for (int m = 0; m < 4; ++m) {
        int row = row0 + ty * 4 + m;
#pragma unroll
        for (int n = 0; n < 4; ++n) {
            int col = col0 + tx * 4 + n;
            if (col >= Ndim) continue;
            float v = acc[m][n];
            if (bias) v += bias[col];
            if constexpr (EPI == EPI_SOFT_BF16) {
                v = softplusf_(v);
                ((ushort_t*)C)[(size_t)row * ldc + col] = f2bf(v);
            } else {
                C[(size_t)row * ldc + col] = v;
            }
        }
    }
}

// ---------------------------------------------------------------------------
// Depthwise causal/anticausal conv K=4 + SiLU. xp [MROWS][DI] fp32.
// ---------------------------------------------------------------------------
__global__ __launch_bounds__(256) void conv_silu_kernel(
    const float* __restrict__ xp,
    const float* __restrict__ cw,
    const float* __restrict__ cb,
    float* __restrict__ xpc,
    int reverse)
{
    int idx = blockIdx.x * 256 + threadIdx.x;
    int c = idx & (DI - 1);
    int row = idx >> 11;
    int t = row & (LL - 1);
    int b = row >> 10;
    float w0 = cw[c * 4 + 0], w1 = cw[c * 4 + 1], w2 = cw[c * 4 + 2], w3 = cw[c * 4 + 3];
    float acc = cb[c];
    if (!reverse) {
#pragma unroll
        for (int k = 0; k < 4; ++k) {
            int tt = t - 3 + k;
            if (tt >= 0) {
                float wv = (k == 0) ? w0 : (k == 1) ? w1 : (k == 2) ? w2 : w3;
                acc = fmaf(wv, xp[(size_t)(b * LL + tt) * DI + c], acc);
            }
        }
    } else {
#pragma unroll
        for (int k = 0; k < 4; ++k) {
            int tt = t + 3 - k;
            if (tt < LL) {
                float wv = (k == 0) ? w0 : (k == 1) ? w1 : (k == 2) ? w2 : w3;
                acc = fmaf(wv, xp[(size_t)(b * LL + tt) * DI + c], acc);
            }
        }
    }
    xpc[idx] = siluf_(acc);
}

// ---------------------------------------------------------------------------
// Chunked scan, phase 1
// ---------------------------------------------------------------------------
__global__ __launch_bounds__(256) void scan_part1(
    const ushort_t* __restrict__ delta_b,  // [MROWS][DI] bf16
    const float* __restrict__ xpc,
    const float* __restrict__ dbl,
    const float* __restrict__ A_log,
    float* __restrict__ chunkS,            // [B][NCH][DI]
    ushort_t* __restrict__ chunkH,         // [B][NCH][DI][NS] bf16
    int reverse)
{
    int c = blockIdx.x * 256 + threadIdx.x;
    int ch = blockIdx.y;
    int b = blockIdx.z;
    int base = b * LL;

    __shared__ float sB[CLEN][16];
    {
        int r = threadIdx.x >> 4;
        int col = threadIdx.x & 15;
        int i = ch * CLEN + r;
        int t = reverse ? (LL - 1 - i) : i;
        sB[r][col] = dbl[(size_t)(base + t) * 96 + RR + col];
    }
    __syncthreads();

    float Ac[NS];
#pragma unroll
    for (int q = 0; q < 4; ++q) {
        float4 a = *reinterpret_cast<const float4*>(&A_log[(size_t)c * NS + q * 4]);
        Ac[q * 4 + 0] = -__expf(a.x);
        Ac[q * 4 + 1] = -__expf(a.y);
        Ac[q * 4 + 2] = -__expf(a.z);
        Ac[q * 4 + 3] = -__expf(a.w);
    }
    float h[NS] = {};
    float S = 0.f;
#pragma unroll
    for (int ii = 0; ii < CLEN; ++ii) {
        int i = ch * CLEN + ii;
        int t = reverse ? (LL - 1 - i) : i;
        size_t row = (size_t)(base + t);
        float dlt = bf2f(delta_b[row * DI + c]);
        float xv = xpc[row * DI + c];
        S += dlt;
        float dx = dlt * xv;
        float4 B0 = *reinterpret_cast<const float4*>(&sB[ii][0]);
        float4 B1 = *reinterpret_cast<const float4*>(&sB[ii][4]);
        float4 B2 = *reinterpret_cast<const float4*>(&sB[ii][8]);
        float4 B3 = *reinterpret_cast<const float4*>(&sB[ii][12]);
        float Bv[NS] = {B0.x, B0.y, B0.z, B0.w, B1.x, B1.y, B1.z, B1.w,
                        B2.x, B2.y, B2.z, B2.w, B3.x, B3.y, B3.z, B3.w};
#pragma unroll
        for (int n = 0; n < NS; ++n)
            h[n] = fmaf(__expf(dlt * Ac[n]), h[n], dx * Bv[n]);
    }
    size_t sidx = ((size_t)(b * NCH + ch)) * DI + c;
    chunkS[sidx] = S;
    ushort_t o[16];
#pragma unroll
    for (int n = 0; n < NS; ++n) o[n] = f2bf(h[n]);
    ushort_t* hp = chunkH + sidx * NS;
    *reinterpret_cast<int4*>(&hp[0]) = *reinterpret_cast<int4*>(&o[0]);
    *reinterpret_cast<int4*>(&hp[8]) = *reinterpret_cast<int4*>(&o[8]);
}

// Phase 2: in-place propagation; afterwards chunkH[b,j,c,:] = h at chunk start
__global__ __launch_bounds__(256) void scan_part2(
    ushort_t* __restrict__ chunkH,
    const float* __restrict__ chunkS,
    const float* __restrict__ A_log)
{
    int idx = blockIdx.x * 256 + threadIdx.x;
    int n = idx & 15;
    int c = (idx >> 4) & (DI - 1);
    int b = idx >> 15;
    float Ac = -__expf(A_log[(size_t)c * NS + n]);
    float cur = 0.f;
    for (int j = 0; j < NCH; ++j) {
        size_t sidx = ((size_t)(b * NCH + j)) * DI + c;
        float S = chunkS[sidx];
        float hf = bf2f(chunkH[sidx * NS + n]);
        float nxt = fmaf(__expf(Ac * S), cur, hf);
        chunkH[sidx * NS + n] = f2bf(cur);
        cur = nxt;
    }
}

// Phase 3: re-scan from h_in, fused C-contraction + D skip + silu(z); bf16 out
__global__ __launch_bounds__(256) void scan_part3(
    const ushort_t* __restrict__ delta_b,
    const float* __restrict__ xpc,
    const float* __restrict__ dbl,
    const ushort_t* __restrict__ zb,      // [MROWS][DI] bf16
    const float* __restrict__ A_log,
    const float* __restrict__ Dp,
    const ushort_t* __restrict__ chunkH,
    ushort_t* __restrict__ ybufb,         // [MROWS][DI] bf16
    int reverse)
{
    int c = blockIdx.x * 256 + threadIdx.x;
    int ch = blockIdx.y;
    int b = blockIdx.z;
    int base = b * LL;

    __shared__ float sBC[CLEN][32];
    for (int r = threadIdx.x >> 5; r < CLEN; r += 8) {
        int col = threadIdx.x & 31;
        int i = ch * CLEN + r;
        int t = reverse ? (LL - 1 - i) : i;
        sBC[r][col] = dbl[(size_t)(base + t) * 96 + RR + col];
    }
    __syncthreads();

    float Ac[NS];
#pragma unroll
    for (int q = 0; q < 4; ++q) {
        float4 a = *reinterpret_cast<const float4*>(&A_log[(size_t)c * NS + q * 4]);
        Ac[q * 4 + 0] = -__expf(a.x);
        Ac[q * 4 + 1] = -__expf(a.y);
        Ac[q * 4 + 2] = -__expf(a.z);
        Ac[q * 4 + 3] = -__expf(a.w);
    }
    size_t sidx = ((size_t)(b * NCH + ch)) * DI + c;
    const ushort_t* hp = chunkH + sidx * NS;
    int4 h0 = *reinterpret_cast<const int4*>(&hp[0]);
    int4 h1 = *reinterpret_cast<const int4*>(&hp[8]);
    const ushort_t* hs0 = reinterpret_cast<const ushort_t*>(&h0);
    const ushort_t* hs1 = reinterpret_cast<const ushort_t*>(&h1);
    float h[NS];
#pragma unroll
    for (int n = 0; n < 8; ++n) { h[n] = bf2f(hs0[n]); h[8 + n] = bf2f(hs1[n]); }
    float Dc = Dp[c];
#pragma unroll
    for (int ii = 0; ii < CLEN; ++ii) {
        int i = ch * CLEN + ii;
        int t = reverse ? (LL - 1 - i) : i;
        size_t row = (size_t)(base + t);
        float dlt = bf2f(delta_b[row * DI + c]);
        float xv = xpc[row * DI + c];
        float dx = dlt * xv;
        float4 B0 = *reinterpret_cast<const float4*>(&sBC[ii][0]);
        float4 B1 = *reinterpret_cast<const float4*>(&sBC[ii][4]);
        float4 B2 = *reinterpret_cast<const float4*>(&sBC[ii][8]);
        float4 B3 = *reinterpret_cast<const float4*>(&sBC[ii][12]);
        float4 C0 = *reinterpret_cast<const float4*>(&sBC[ii][16]);
        float4 C1 = *reinterpret_cast<const float4*>(&sBC[ii][20]);
        float4 C2 = *reinterpret_cast<const float4*>(&sBC[ii][24]);
        float4 C3 = *reinterpret_cast<const float4*>(&sBC[ii][28]);
        float Bv[NS] = {B0.x, B0.y, B0.z, B0.w, B1.x, B1.y, B1.z, B1.w,
                        B2.x, B2.y, B2.z, B2.w, B3.x, B3.y, B3.z, B3.w};
        float Cv[NS] = {C0.x, C0.y, C0.z, C0.w, C1.x, C1.y, C1.z, C1.w,
                        C2.x, C2.y, C2.z, C2.w, C3.x, C3.y, C3.z, C3.w};
        float y = 0.f;
#pragma unroll
        for (int n = 0; n < NS; ++n) {
            h[n] = fmaf(__expf(dlt * Ac[n]), h[n], dx * Bv[n]);
            y = fmaf(h[n], Cv[n], y);
        }
        float z = bf2f(zb[row * DI + c]);
        ybufb[row * DI + c] = f2bf((y + xv * Dc) * siluf_(z));
    }
}

// ---------------------------------------------------------------------------
extern "C" void kernel_launch(void* const* d_in, const int* in_sizes, int n_in,
                              void* d_out, int out_size, void* d_ws, size_t ws_size,
                              hipStream_t stream)
{
    const float* x      = (const float*)d_in[0];
    const float* ln_w   = (const float*)d_in[1];
    const float* ln_b   = (const float*)d_in[2];
    const float* W_in   = (const float*)d_in[3];
    const float* b_in   = (const float*)d_in[4];
    const float* conv_w = (const float*)d_in[5];
    const float* conv_b = (const float*)d_in[6];
    const float* W_xproj= (const float*)d_in[7];
    const float* W_dt   = (const float*)d_in[8];
    const float* b_dt   = (const float*)d_in[9];
    const float* A_log  = (const float*)d_in[10];
    const float* Dp     = (const float*)d_in[11];
    const float* W_out  = (const float*)d_in[12];
    const float* b_out  = (const float*)d_in[13];
    const float* Wg     = (const float*)d_in[14];
    const float* bg     = (const float*)d_in[15];
    const float* Wv     = (const float*)d_in[16];
    const float* bv     = (const float*)d_in[17];
    float* out = (float*)d_out;

    // ---- workspace layout (fp32 region, then bf16 region) ----
    float* ws = (float*)d_ws;
    size_t off = 0;
    float* xp    = ws + off; off += (size_t)MROWS * DI;        // 4M f
    float* xpc   = ws + off; off += (size_t)MROWS * DI;        // 4M f
    float* dblb  = ws + off; off += (size_t)MROWS * 96;
    float* comb  = ws + off; off += (size_t)MROWS * 2 * DM;    // 4M f
    float* chS   = ws + off; off += (size_t)BB * NCH * DI;     // 0.25M f
    ushort_t* sbase = (ushort_t*)(ws + off);
    size_t soff = 0;
    ushort_t* xlnb   = sbase + soff; soff += (size_t)MROWS * DM;        // 2M sh
    ushort_t* zb     = sbase + soff; soff += (size_t)MROWS * DI;        // 4M sh
    ushort_t* deltab = sbase + soff; soff += (size_t)MROWS * DI;        // 4M sh
    ushort_t* ybufb  = sbase + soff; soff += (size_t)MROWS * DI;        // 4M sh
    ushort_t* chHb   = sbase + soff; soff += (size_t)BB * NCH * DI * NS;// 4M sh
    ushort_t* WTin   = sbase + soff; soff += (size_t)(2 * DI) * DM;     // 4M sh
    ushort_t* WTout  = sbase + soff; soff += (size_t)2 * DM * DI;       // 4M sh
    ushort_t* WTgv   = sbase + soff; soff += (size_t)2 * DM * (2 * DM); // 4M sh

    // ---- weight transpose-casts (direction-independent ones) ----
    // W_out [2][DI][DM] -> WTout [2][DM][DI]
    tcast<<<dim3(DM / 64, DI / 64, 2), 256, 0, stream>>>(
        W_out, (long)DI * DM, WTout, (long)DM * DI, DI, DM);
    // Wg [2DM][DM] -> WTgv[0] [DM][2DM]
    tcast<<<dim3(DM / 64, (2 * DM) / 64, 1), 256, 0, stream>>>(
        Wg, 0, WTgv, 0, 2 * DM, DM);
    // Wv -> WTgv[1]
    tcast<<<dim3(DM / 64, (2 * DM) / 64, 1), 256, 0, stream>>>(
        Wv, 0, WTgv + (size_t)DM * 2 * DM, 0, 2 * DM, DM);

    for (int d = 0; d < 2; ++d) {
        const float* Alg = A_log + (size_t)d * DI * NS;
        // W_in[d] [DM][2DI] -> WTin [2DI][DM]
        tcast<<<dim3((2 * DI) / 64, DM / 64, 1), 256, 0, stream>>>(
            W_in + (size_t)d * DM * 2 * DI, 0, WTin, 0, DM, 2 * DI);
        // LN -> bf16
        ln_kernel<<<MROWS, 256, 0, stream>>>(
            x, ln_w + (size_t)d * DM, ln_b + (size_t)d * DM, xlnb);
        // xz = xln @ W_in + b_in : xp fp32 (cols<DI), zb bf16 (cols>=DI)
        gemm_bf<EPI_XPZ><<<dim3((2 * DI) / 128, MROWS / 128), 256, 0, stream>>>(
            xlnb, DM, WTin, DM, b_in + (size_t)d * 2 * DI,
            xp, DI, zb, DI, nullptr, 0, DM);
        // conv + silu
        conv_silu_kernel<<<(MROWS * DI) / 256, 256, 0, stream>>>(
            xp, conv_w + (size_t)d * DI * 4, conv_b + (size_t)d * DI, xpc, d);
        // dbl = xpc @ W_xproj (fp32)
        gemm64<EPI_BIAS><<<dim3(2, MROWS / 64), 256, 0, stream>>>(
            xpc, DI, W_xproj + (size_t)d * DI * 96, 96, nullptr,
            dblb, 96, 96, DI);
        // delta = softplus(dt @ W_dt + b_dt) -> bf16
        gemm64<EPI_SOFT_BF16><<<dim3(DI / 64, MROWS / 64), 256, 0, stream>>>(
            dblb, 96, W_dt + (size_t)d * RR * DI, DI, b_dt + (size_t)d * DI,
            (float*)deltab, DI, DI, RR);
        // chunked scan
        scan_part1<<<dim3(DI / 256, NCH, BB), 256, 0, stream>>>(
            deltab, xpc, dblb, Alg, chS, chHb, d);
        scan_part2<<<(BB * DI * NS) / 256, 256, 0, stream>>>(chHb, chS, Alg);
        scan_part3<<<dim3(DI / 256, NCH, BB), 256, 0, stream>>>(
            deltab, xpc, dblb, zb, Alg, Dp + (size_t)d * DI, chHb, ybufb, d);
        // comb[:, d*DM:] = x + ybuf @ W_out + b_out
        gemm_bf<EPI_COMB><<<dim3(DM / 128, MROWS / 128), 256, 0, stream>>>(
            ybufb, DI, WTout + (size_t)d * DM * DI, DI, b_out + (size_t)d * DM,
            comb + (size_t)d * DM, 2 * DM, nullptr, 0, x, DM, DI);
    }

    // final fused dual GEMM + mix
    gemm_final<<<dim3(DM / 128, MROWS / 128), 256, 0, stream>>>(
        comb, 2 * DM, WTgv, WTgv + (size_t)DM * 2 * DM, 2 * DM, bg, bv, out);
}

// Round 4
// 692.579 us; speedup vs baseline: 4.5585x; 1.2026x over previous
//
#include <hip/hip_runtime.h>
#include <math.h>

constexpr int BB = 2;
constexpr int LL = 1024;
constexpr int DM = 1024;
constexpr int DI = 2048;
constexpr int NS = 16;
constexpr int RR = 64;
constexpr int MROWS = BB * LL;

constexpr int CLEN = 16;
constexpr int NCH = LL / CLEN;  // 64

constexpr int LDT = 40;         // LDS row stride (shorts) for 32-k tiles + pad

constexpr int NSPLIT = 16;      // split-K slices for xproj
constexpr int KCH = DI / NSPLIT; // 128

#define DEV __device__ __forceinline__

typedef unsigned short ushort_t;
using bf16x8 = __attribute__((ext_vector_type(8))) short;
using f32x4  = __attribute__((ext_vector_type(4))) float;

DEV float sigmoidf_(float x) { return 1.f / (1.f + expf(-x)); }
DEV float siluf_(float x) { return x * sigmoidf_(x); }
DEV float softplusf_(float x) { return (x > 20.f) ? x : log1pf(expf(x)); }

DEV ushort_t f2bf(float x) {
    union { float f; unsigned u; } v; v.f = x;
    unsigned r = v.u + 0x7FFFu + ((v.u >> 16) & 1u);
    return (ushort_t)(r >> 16);
}
DEV float bf2f(ushort_t u) {
    union { unsigned u; float f; } v; v.u = ((unsigned)u) << 16;
    return v.f;
}
DEV int4 cvt8(float4 a, float4 b) {
    ushort_t o[8] = {f2bf(a.x), f2bf(a.y), f2bf(a.z), f2bf(a.w),
                     f2bf(b.x), f2bf(b.y), f2bf(b.z), f2bf(b.w)};
    return *reinterpret_cast<int4*>(o);
}

// ---------------------------------------------------------------------------
// Transpose-cast: in fp32 [R][C] -> out bf16 [C][R]. 64x64 tiles (R,C %64==0).
// ---------------------------------------------------------------------------
__global__ __launch_bounds__(256) void tcast(
    const float* __restrict__ in, long sIn,
    ushort_t* __restrict__ outT, long sOut,
    int R, int C)
{
    in += (size_t)blockIdx.z * sIn;
    outT += (size_t)blockIdx.z * sOut;
    __shared__ float tile[64][65];
    int r0 = blockIdx.y * 64, c0 = blockIdx.x * 64;
#pragma unroll
    for (int i = 0; i < 4; ++i) {
        int r = (threadIdx.x >> 4) + i * 16;
        int c4 = (threadIdx.x & 15) * 4;
        float4 v = *reinterpret_cast<const float4*>(&in[(size_t)(r0 + r) * C + c0 + c4]);
        tile[r][c4] = v.x; tile[r][c4 + 1] = v.y; tile[r][c4 + 2] = v.z; tile[r][c4 + 3] = v.w;
    }
    __syncthreads();
#pragma unroll
    for (int i = 0; i < 2; ++i) {
        int c = (threadIdx.x >> 3) + i * 32;
        int r8 = (threadIdx.x & 7) * 8;
        ushort_t o[8];
#pragma unroll
        for (int j = 0; j < 8; ++j) o[j] = f2bf(tile[r8 + j][c]);
        *reinterpret_cast<int4*>(&outT[(size_t)(c0 + c) * R + r0 + r8]) =
            *reinterpret_cast<int4*>(o);
    }
}

// Guarded scalar transpose-cast for odd shapes (W_xproj [DI][96] -> [96][DI]).
__global__ __launch_bounds__(256) void tcastP(
    const float* __restrict__ in, long sIn,
    ushort_t* __restrict__ outT, long sOut,
    int R, int C)
{
    in += (size_t)blockIdx.z * sIn;
    outT += (size_t)blockIdx.z * sOut;
    int idx = blockIdx.x * 256 + threadIdx.x;
    if (idx >= R * C) return;
    int r = idx / C, c = idx - r * C;
    outT[(size_t)c * R + r] = f2bf(in[idx]);
}

// ---------------------------------------------------------------------------
// LayerNorm (one direction) -> bf16 output
// ---------------------------------------------------------------------------
__global__ __launch_bounds__(256) void ln_kernel(
    const float* __restrict__ x,
    const float* __restrict__ ln_w,
    const float* __restrict__ ln_b,
    ushort_t* __restrict__ xlnb)
{
    int row = blockIdx.x;
    const float* xr = x + (size_t)row * DM;
    int i4 = threadIdx.x * 4;
    float4 v = *reinterpret_cast<const float4*>(&xr[i4]);
    float s = v.x + v.y + v.z + v.w;
    float s2 = v.x * v.x + v.y * v.y + v.z * v.z + v.w * v.w;
    for (int off = 32; off > 0; off >>= 1) {
        s += __shfl_down(s, off);
        s2 += __shfl_down(s2, off);
    }
    __shared__ float sbuf[10];
    int wid = threadIdx.x >> 6;
    if ((threadIdx.x & 63) == 0) { sbuf[wid] = s; sbuf[4 + wid] = s2; }
    __syncthreads();
    if (threadIdx.x == 0) {
        float S = sbuf[0] + sbuf[1] + sbuf[2] + sbuf[3];
        float S2 = sbuf[4] + sbuf[5] + sbuf[6] + sbuf[7];
        float mu = S / DM;
        float var = S2 / DM - mu * mu;
        sbuf[8] = mu;
        sbuf[9] = rsqrtf(var + 1e-5f);
    }
    __syncthreads();
    float mu = sbuf[8], rstd = sbuf[9];
    float4 w = *reinterpret_cast<const float4*>(&ln_w[i4]);
    float4 b = *reinterpret_cast<const float4*>(&ln_b[i4]);
    ushort_t o[4];
    o[0] = f2bf((v.x - mu) * rstd * w.x + b.x);
    o[1] = f2bf((v.y - mu) * rstd * w.y + b.y);
    o[2] = f2bf((v.z - mu) * rstd * w.z + b.z);
    o[3] = f2bf((v.w - mu) * rstd * w.w + b.w);
    *reinterpret_cast<uint2*>(&xlnb[(size_t)row * DM + i4]) = *reinterpret_cast<uint2*>(o);
}

// ---------------------------------------------------------------------------
// bf16 MFMA GEMM, 128x128 tile, 4 waves (2x2), BK=32.
// EPI_XPZ: cols<DI -> fp32 xp; cols>=DI -> bf16 zb
// EPI_COMB: out fp32 = acc+bias+res
// EPI_SOFT: out bf16 = softplus(acc+bias)
// ---------------------------------------------------------------------------
enum { EPI_XPZ = 0, EPI_COMB = 1, EPI_SOFT = 2 };

template <int EPI>
__global__ __launch_bounds__(256) void gemm_bf(
    const ushort_t* __restrict__ A, int lda,
    const ushort_t* __restrict__ Bt, int ldb,
    const float* __restrict__ bias,
    float* __restrict__ outF, int ldof,
    ushort_t* __restrict__ outB, int ldob,
    const float* __restrict__ res, int ldres,
    int Kdim)
{
    __shared__ ushort_t As[128 * LDT];
    __shared__ ushort_t Bs[128 * LDT];
    int tid = threadIdx.x;
    int lane = tid & 63;
    int w = tid >> 6, wr = w >> 1, wc = w & 1;
    int lrow = lane & 15, lk = lane >> 4;
    int row0 = blockIdx.y * 128, col0 = blockIdx.x * 128;

    f32x4 acc[4][4];
#pragma unroll
    for (int m = 0; m < 4; ++m)
#pragma unroll
        for (int n = 0; n < 4; ++n) acc[m][n] = {0.f, 0.f, 0.f, 0.f};

    int sr = tid >> 2, ss = tid & 3;
    const ushort_t* ga0 = A + (size_t)(row0 + sr) * lda + ss * 8;
    const ushort_t* ga1 = A + (size_t)(row0 + sr + 64) * lda + ss * 8;
    const ushort_t* gb0 = Bt + (size_t)(col0 + sr) * ldb + ss * 8;
    const ushort_t* gb1 = Bt + (size_t)(col0 + sr + 64) * ldb + ss * 8;

    for (int k0 = 0; k0 < Kdim; k0 += 32) {
        int4 a0 = *reinterpret_cast<const int4*>(ga0);
        int4 a1 = *reinterpret_cast<const int4*>(ga1);
        int4 b0 = *reinterpret_cast<const int4*>(gb0);
        int4 b1 = *reinterpret_cast<const int4*>(gb1);
        ga0 += 32; ga1 += 32; gb0 += 32; gb1 += 32;
        __syncthreads();
        *reinterpret_cast<int4*>(&As[sr * LDT + ss * 8]) = a0;
        *reinterpret_cast<int4*>(&As[(sr + 64) * LDT + ss * 8]) = a1;
        *reinterpret_cast<int4*>(&Bs[sr * LDT + ss * 8]) = b0;
        *reinterpret_cast<int4*>(&Bs[(sr + 64) * LDT + ss * 8]) = b1;
        __syncthreads();
        bf16x8 af[4], bfr[4];
#pragma unroll
        for (int m = 0; m < 4; ++m)
            af[m] = *reinterpret_cast<const bf16x8*>(&As[(wr * 64 + m * 16 + lrow) * LDT + lk * 8]);
#pragma unroll
        for (int n = 0; n < 4; ++n)
            bfr[n] = *reinterpret_cast<const bf16x8*>(&Bs[(wc * 64 + n * 16 + lrow) * LDT + lk * 8]);
#pragma unroll
        for (int m = 0; m < 4; ++m)
#pragma unroll
            for (int n = 0; n < 4; ++n)
                acc[m][n] = __builtin_amdgcn_mfma_f32_16x16x32_bf16(af[m], bfr[n], acc[m][n], 0, 0, 0);
    }

#pragma unroll
    for (int n = 0; n < 4; ++n) {
        int col = col0 + wc * 64 + n * 16 + lrow;
        float bv = bias[col];
#pragma unroll
        for (int m = 0; m < 4; ++m) {
#pragma unroll
            for (int rr = 0; rr < 4; ++rr) {
                int row = row0 + wr * 64 + m * 16 + lk * 4 + rr;
                float v = acc[m][n][rr] + bv;
                if constexpr (EPI == EPI_XPZ) {
                    if (col < DI) outF[(size_t)row * ldof + col] = v;
                    else outB[(size_t)row * ldob + (col - DI)] = f2bf(v);
                } else if constexpr (EPI == EPI_COMB) {
                    v += res[(size_t)row * ldres + col];
                    outF[(size_t)row * ldof + col] = v;
                } else {
                    outB[(size_t)row * ldob + col] = f2bf(softplusf_(v));
                }
            }
        }
    }
}

// ---------------------------------------------------------------------------
// Split-K MFMA GEMM for xproj: A[M][DI] bf16 x Bt[96][DI] bf16 -> partials.
// Grid: (NSPLIT, MROWS/128). Block 256 (4 waves, 2x2), per-wave 4x3 frags.
// ---------------------------------------------------------------------------
__global__ __launch_bounds__(256) void gemm_xproj(
    const ushort_t* __restrict__ A,
    const ushort_t* __restrict__ Bt,
    float* __restrict__ part)         // [NSPLIT][MROWS][96]
{
    __shared__ ushort_t As[128 * LDT];
    __shared__ ushort_t Bs[96 * LDT];
    int tid = threadIdx.x;
    int lane = tid & 63;
    int w = tid >> 6, wr = w >> 1, wc = w & 1;
    int lrow = lane & 15, lk = lane >> 4;
    int s = blockIdx.x, rt = blockIdx.y;
    int row0 = rt * 128;
    int k0 = s * KCH;

    f32x4 acc[4][3];
#pragma unroll
    for (int m = 0; m < 4; ++m)
#pragma unroll
        for (int n = 0; n < 3; ++n) acc[m][n] = {0.f, 0.f, 0.f, 0.f};

    int sr = tid >> 2, ss = tid & 3;
    const ushort_t* ga0 = A + (size_t)(row0 + sr) * DI + k0 + ss * 8;
    const ushort_t* ga1 = A + (size_t)(row0 + sr + 64) * DI + k0 + ss * 8;

    for (int kk = 0; kk < KCH; kk += 32) {
        int4 a0 = *reinterpret_cast<const int4*>(ga0);
        int4 a1 = *reinterpret_cast<const int4*>(ga1);
        ga0 += 32; ga1 += 32;
        __syncthreads();
        *reinterpret_cast<int4*>(&As[sr * LDT + ss * 8]) = a0;
        *reinterpret_cast<int4*>(&As[(sr + 64) * LDT + ss * 8]) = a1;
        for (int i = tid; i < 96 * 4; i += 256) {
            int br = i >> 2, bs = i & 3;
            *reinterpret_cast<int4*>(&Bs[br * LDT + bs * 8]) =
                *reinterpret_cast<const int4*>(&Bt[(size_t)br * DI + k0 + kk + bs * 8]);
        }
        __syncthreads();
        bf16x8 af[4], bfr[3];
#pragma unroll
        for (int m = 0; m < 4; ++m)
            af[m] = *reinterpret_cast<const bf16x8*>(&As[(wr * 64 + m * 16 + lrow) * LDT + lk * 8]);
#pragma unroll
        for (int n = 0; n < 3; ++n)
            bfr[n] = *reinterpret_cast<const bf16x8*>(&Bs[(wc * 48 + n * 16 + lrow) * LDT + lk * 8]);
#pragma unroll
        for (int m = 0; m < 4; ++m)
#pragma unroll
            for (int n = 0; n < 3; ++n)
                acc[m][n] = __builtin_amdgcn_mfma_f32_16x16x32_bf16(af[m], bfr[n], acc[m][n], 0, 0, 0);
    }

#pragma unroll
    for (int n = 0; n < 3; ++n) {
        int col = wc * 48 + n * 16 + lrow;
#pragma unroll
        for (int m = 0; m < 4; ++m) {
#pragma unroll
            for (int rr = 0; rr < 4; ++rr) {
                int row = row0 + wr * 64 + m * 16 + lk * 4 + rr;
                part[((size_t)s * MROWS + row) * 96 + col] = acc[m][n][rr];
            }
        }
    }
}

// Sum NSPLIT partials -> dblf fp32 [MROWS][96]; cols<RR also -> dt bf16 [MROWS][RR]
__global__ __launch_bounds__(256) void dbl_reduce(
    const float* __restrict__ part,
    float* __restrict__ dblf,
    ushort_t* __restrict__ dtb)
{
    int idx = blockIdx.x * 256 + threadIdx.x;   // MROWS*96
    int row = idx / 96, col = idx - row * 96;
    float v = 0.f;
#pragma unroll
    for (int s = 0; s < NSPLIT; ++s)
        v += part[((size_t)s * MROWS + row) * 96 + col];
    dblf[idx] = v;
    if (col < RR) dtb[(size_t)row * RR + col] = f2bf(v);
}

// ---------------------------------------------------------------------------
// Final fused GEMM: dual-B (Wg, Wv)
// ---------------------------------------------------------------------------
__global__ __launch_bounds__(256) void gemm_final(
    const float* __restrict__ comb, int lda,
    const ushort_t* __restrict__ Bg, const ushort_t* __restrict__ Bv, int ldb,
    const float* __restrict__ bg, const float* __restrict__ bvp,
    float* __restrict__ out)
{
    __shared__ ushort_t As[128 * LDT];
    __shared__ ushort_t Bs1[128 * LDT];
    __shared__ ushort_t Bs2[128 * LDT];
    int tid = threadIdx.x;
    int lane = tid & 63;
    int w = tid >> 6, wr = w >> 1, wc = w & 1;
    int lrow = lane & 15, lk = lane >> 4;
    int row0 = blockIdx.y * 128, col0 = blockIdx.x * 128;

    f32x4 accg[4][4], accv[4][4];
#pragma unroll
    for (int m = 0; m < 4; ++m)
#pragma unroll
        for (int n = 0; n < 4; ++n) { accg[m][n] = {0.f,0.f,0.f,0.f}; accv[m][n] = {0.f,0.f,0.f,0.f}; }

    int sr = tid >> 2, ss = tid & 3;
    const float* gaf0 = comb + (size_t)(row0 + sr) * lda + ss * 8;
    const float* gaf1 = comb + (size_t)(row0 + sr + 64) * lda + ss * 8;
    const ushort_t* gb0 = Bg + (size_t)(col0 + sr) * ldb + ss * 8;
    const ushort_t* gb1 = Bg + (size_t)(col0 + sr + 64) * ldb + ss * 8;
    const ushort_t* gc0 = Bv + (size_t)(col0 + sr) * ldb + ss * 8;
    const ushort_t* gc1 = Bv + (size_t)(col0 + sr + 64) * ldb + ss * 8;

    for (int k0 = 0; k0 < 2 * DM; k0 += 32) {
        float4 a00 = *reinterpret_cast<const float4*>(gaf0);
        float4 a01 = *reinterpret_cast<const float4*>(gaf0 + 4);
        float4 a10 = *reinterpret_cast<const float4*>(gaf1);
        float4 a11 = *reinterpret_cast<const float4*>(gaf1 + 4);
        int4 b0 = *reinterpret_cast<const int4*>(gb0);
        int4 b1 = *reinterpret_cast<const int4*>(gb1);
        int4 c0 = *reinterpret_cast<const int4*>(gc0);
        int4 c1 = *reinterpret_cast<const int4*>(gc1);
        gaf0 += 32; gaf1 += 32; gb0 += 32; gb1 += 32; gc0 += 32; gc1 += 32;
        int4 pa0 = cvt8(a00, a01);
        int4 pa1 = cvt8(a10, a11);
        __syncthreads();
        *reinterpret_cast<int4*>(&As[sr * LDT + ss * 8]) = pa0;
        *reinterpret_cast<int4*>(&As[(sr + 64) * LDT + ss * 8]) = pa1;
        *reinterpret_cast<int4*>(&Bs1[sr * LDT + ss * 8]) = b0;
        *reinterpret_cast<int4*>(&Bs1[(sr + 64) * LDT + ss * 8]) = b1;
        *reinterpret_cast<int4*>(&Bs2[sr * LDT + ss * 8]) = c0;
        *reinterpret_cast<int4*>(&Bs2[(sr + 64) * LDT + ss * 8]) = c1;
        __syncthreads();
        bf16x8 af[4], bf1[4], bf2[4];
#pragma unroll
        for (int m = 0; m < 4; ++m)
            af[m] = *reinterpret_cast<const bf16x8*>(&As[(wr * 64 + m * 16 + lrow) * LDT + lk * 8]);
#pragma unroll
        for (int n = 0; n < 4; ++n) {
            bf1[n] = *reinterpret_cast<const bf16x8*>(&Bs1[(wc * 64 + n * 16 + lrow) * LDT + lk * 8]);
            bf2[n] = *reinterpret_cast<const bf16x8*>(&Bs2[(wc * 64 + n * 16 + lrow) * LDT + lk * 8]);
        }
#pragma unroll
        for (int m = 0; m < 4; ++m)
#pragma unroll
            for (int n = 0; n < 4; ++n) {
                accg[m][n] = __builtin_amdgcn_mfma_f32_16x16x32_bf16(af[m], bf1[n], accg[m][n], 0, 0, 0);
                accv[m][n] = __builtin_amdgcn_mfma_f32_16x16x32_bf16(af[m], bf2[n], accv[m][n], 0, 0, 0);
            }
    }

#pragma unroll
    for (int n = 0; n < 4; ++n) {
        int col = col0 + wc * 64 + n * 16 + lrow;
        float bgv = bg[col];
        float bvv = bvp[col];
#pragma unroll
        for (int m = 0; m < 4; ++m) {
#pragma unroll
            for (int rr = 0; rr < 4; ++rr) {
                int row = row0 + wr * 64 + m * 16 + lk * 4 + rr;
                float g = sigmoidf_(accg[m][n][rr] + bgv);
                float v = accv[m][n][rr] + bvv;
                float f = comb[(size_t)row * lda + col];
                float wv2 = comb[(size_t)row * lda + DM + col];
                out[(size_t)row * DM + col] = 0.5f * (g * v + (1.f - g) * (f + wv2));
            }
        }
    }
}

// ---------------------------------------------------------------------------
// Depthwise conv K=4 + SiLU -> fp32 xpc (scan) + bf16 xpcb (GEMMs)
// ---------------------------------------------------------------------------
__global__ __launch_bounds__(256) void conv_silu_kernel(
    const float* __restrict__ xp,
    const float* __restrict__ cw,
    const float* __restrict__ cb,
    float* __restrict__ xpc,
    ushort_t* __restrict__ xpcb,
    int reverse)
{
    int idx = blockIdx.x * 256 + threadIdx.x;
    int c = idx & (DI - 1);
    int row = idx >> 11;
    int t = row & (LL - 1);
    int b = row >> 10;
    float w0 = cw[c * 4 + 0], w1 = cw[c * 4 + 1], w2 = cw[c * 4 + 2], w3 = cw[c * 4 + 3];
    float acc = cb[c];
    if (!reverse) {
#pragma unroll
        for (int k = 0; k < 4; ++k) {
            int tt = t - 3 + k;
            if (tt >= 0) {
                float wv = (k == 0) ? w0 : (k == 1) ? w1 : (k == 2) ? w2 : w3;
                acc = fmaf(wv, xp[(size_t)(b * LL + tt) * DI + c], acc);
            }
        }
    } else {
#pragma unroll
        for (int k = 0; k < 4; ++k) {
            int tt = t + 3 - k;
            if (tt < LL) {
                float wv = (k == 0) ? w0 : (k == 1) ? w1 : (k == 2) ? w2 : w3;
                acc = fmaf(wv, xp[(size_t)(b * LL + tt) * DI + c], acc);
            }
        }
    }
    float r = siluf_(acc);
    xpc[idx] = r;
    xpcb[idx] = f2bf(r);
}

// ---------------------------------------------------------------------------
// Chunked scan, phase 1
// ---------------------------------------------------------------------------
__global__ __launch_bounds__(256) void scan_part1(
    const ushort_t* __restrict__ delta_b,
    const float* __restrict__ xpc,
    const float* __restrict__ dbl,
    const float* __restrict__ A_log,
    float* __restrict__ chunkS,
    ushort_t* __restrict__ chunkH,
    int reverse)
{
    int c = blockIdx.x * 256 + threadIdx.x;
    int ch = blockIdx.y;
    int b = blockIdx.z;
    int base = b * LL;

    __shared__ float sB[CLEN][16];
    {
        int r = threadIdx.x >> 4;
        int col = threadIdx.x & 15;
        int i = ch * CLEN + r;
        int t = reverse ? (LL - 1 - i) : i;
        sB[r][col] = dbl[(size_t)(base + t) * 96 + RR + col];
    }
    __syncthreads();

    float Ac[NS];
#pragma unroll
    for (int q = 0; q < 4; ++q) {
        float4 a = *reinterpret_cast<const float4*>(&A_log[(size_t)c * NS + q * 4]);
        Ac[q * 4 + 0] = -__expf(a.x);
        Ac[q * 4 + 1] = -__expf(a.y);
        Ac[q * 4 + 2] = -__expf(a.z);
        Ac[q * 4 + 3] = -__expf(a.w);
    }
    float h[NS] = {};
    float S = 0.f;
#pragma unroll
    for (int ii = 0; ii < CLEN; ++ii) {
        int i = ch * CLEN + ii;
        int t = reverse ? (LL - 1 - i) : i;
        size_t row = (size_t)(base + t);
        float dlt = bf2f(delta_b[row * DI + c]);
        float xv = xpc[row * DI + c];
        S += dlt;
        float dx = dlt * xv;
        float4 B0 = *reinterpret_cast<const float4*>(&sB[ii][0]);
        float4 B1 = *reinterpret_cast<const float4*>(&sB[ii][4]);
        float4 B2 = *reinterpret_cast<const float4*>(&sB[ii][8]);
        float4 B3 = *reinterpret_cast<const float4*>(&sB[ii][12]);
        float Bv[NS] = {B0.x, B0.y, B0.z, B0.w, B1.x, B1.y, B1.z, B1.w,
                        B2.x, B2.y, B2.z, B2.w, B3.x, B3.y, B3.z, B3.w};
#pragma unroll
        for (int n = 0; n < NS; ++n)
            h[n] = fmaf(__expf(dlt * Ac[n]), h[n], dx * Bv[n]);
    }
    size_t sidx = ((size_t)(b * NCH + ch)) * DI + c;
    chunkS[sidx] = S;
    ushort_t o[16];
#pragma unroll
    for (int n = 0; n < NS; ++n) o[n] = f2bf(h[n]);
    ushort_t* hp = chunkH + sidx * NS;
    *reinterpret_cast<int4*>(&hp[0]) = *reinterpret_cast<int4*>(&o[0]);
    *reinterpret_cast<int4*>(&hp[8]) = *reinterpret_cast<int4*>(&o[8]);
}

// Phase 2
__global__ __launch_bounds__(256) void scan_part2(
    ushort_t* __restrict__ chunkH,
    const float* __restrict__ chunkS,
    const float* __restrict__ A_log)
{
    int idx = blockIdx.x * 256 + threadIdx.x;
    int n = idx & 15;
    int c = (idx >> 4) & (DI - 1);
    int b = idx >> 15;
    float Ac = -__expf(A_log[(size_t)c * NS + n]);
    float cur = 0.f;
    for (int j = 0; j < NCH; ++j) {
        size_t sidx = ((size_t)(b * NCH + j)) * DI + c;
        float S = chunkS[sidx];
        float hf = bf2f(chunkH[sidx * NS + n]);
        float nxt = fmaf(__expf(Ac * S), cur, hf);
        chunkH[sidx * NS + n] = f2bf(cur);
        cur = nxt;
    }
}

// Phase 3
__global__ __launch_bounds__(256) void scan_part3(
    const ushort_t* __restrict__ delta_b,
    const float* __restrict__ xpc,
    const float* __restrict__ dbl,
    const ushort_t* __restrict__ zb,
    const float* __restrict__ A_log,
    const float* __restrict__ Dp,
    const ushort_t* __restrict__ chunkH,
    ushort_t* __restrict__ ybufb,
    int reverse)
{
    int c = blockIdx.x * 256 + threadIdx.x;
    int ch = blockIdx.y;
    int b = blockIdx.z;
    int base = b * LL;

    __shared__ float sBC[CLEN][32];
    for (int r = threadIdx.x >> 5; r < CLEN; r += 8) {
        int col = threadIdx.x & 31;
        int i = ch * CLEN + r;
        int t = reverse ? (LL - 1 - i) : i;
        sBC[r][col] = dbl[(size_t)(base + t) * 96 + RR + col];
    }
    __syncthreads();

    float Ac[NS];
#pragma unroll
    for (int q = 0; q < 4; ++q) {
        float4 a = *reinterpret_cast<const float4*>(&A_log[(size_t)c * NS + q * 4]);
        Ac[q * 4 + 0] = -__expf(a.x);
        Ac[q * 4 + 1] = -__expf(a.y);
        Ac[q * 4 + 2] = -__expf(a.z);
        Ac[q * 4 + 3] = -__expf(a.w);
    }
    size_t sidx = ((size_t)(b * NCH + ch)) * DI + c;
    const ushort_t* hp = chunkH + sidx * NS;
    int4 h0 = *reinterpret_cast<const int4*>(&hp[0]);
    int4 h1 = *reinterpret_cast<const int4*>(&hp[8]);
    const ushort_t* hs0 = reinterpret_cast<const ushort_t*>(&h0);
    const ushort_t* hs1 = reinterpret_cast<const ushort_t*>(&h1);
    float h[NS];
#pragma unroll
    for (int n = 0; n < 8; ++n) { h[n] = bf2f(hs0[n]); h[8 + n] = bf2f(hs1[n]); }
    float Dc = Dp[c];
#pragma unroll
    for (int ii = 0; ii < CLEN; ++ii) {
        int i = ch * CLEN + ii;
        int t = reverse ? (LL - 1 - i) : i;
        size_t row = (size_t)(base + t);
        float dlt = bf2f(delta_b[row * DI + c]);
        float xv = xpc[row * DI + c];
        float dx = dlt * xv;
        float4 B0 = *reinterpret_cast<const float4*>(&sBC[ii][0]);
        float4 B1 = *reinterpret_cast<const float4*>(&sBC[ii][4]);
        float4 B2 = *reinterpret_cast<const float4*>(&sBC[ii][8]);
        float4 B3 = *reinterpret_cast<const float4*>(&sBC[ii][12]);
        float4 C0 = *reinterpret_cast<const float4*>(&sBC[ii][16]);
        float4 C1 = *reinterpret_cast<const float4*>(&sBC[ii][20]);
        float4 C2 = *reinterpret_cast<const float4*>(&sBC[ii][24]);
        float4 C3 = *reinterpret_cast<const float4*>(&sBC[ii][28]);
        float Bv[NS] = {B0.x, B0.y, B0.z, B0.w, B1.x, B1.y, B1.z, B1.w,
                        B2.x, B2.y, B2.z, B2.w, B3.x, B3.y, B3.z, B3.w};
        float Cv[NS] = {C0.x, C0.y, C0.z, C0.w, C1.x, C1.y, C1.z, C1.w,
                        C2.x, C2.y, C2.z, C2.w, C3.x, C3.y, C3.z, C3.w};
        float y = 0.f;
#pragma unroll
        for (int n = 0; n < NS; ++n) {
            h[n] = fmaf(__expf(dlt * Ac[n]), h[n], dx * Bv[n]);
            y = fmaf(h[n], Cv[n], y);
        }
        float z = bf2f(zb[row * DI + c]);
        ybufb[row * DI + c] = f2bf((y + xv * Dc) * siluf_(z));
    }
}

// ---------------------------------------------------------------------------
extern "C" void kernel_launch(void* const* d_in, const int* in_sizes, int n_in,
                              void* d_out, int out_size, void* d_ws, size_t ws_size,
                              hipStream_t stream)
{
    const float* x      = (const float*)d_in[0];
    const float* ln_w   = (const float*)d_in[1];
    const float* ln_b   = (const float*)d_in[2];
    const float* W_in   = (const float*)d_in[3];
    const float* b_in   = (const float*)d_in[4];
    const float* conv_w = (const float*)d_in[5];
    const float* conv_b = (const float*)d_in[6];
    const float* W_xproj= (const float*)d_in[7];
    const float* W_dt   = (const float*)d_in[8];
    const float* b_dt   = (const float*)d_in[9];
    const float* A_log  = (const float*)d_in[10];
    const float* Dp     = (const float*)d_in[11];
    const float* W_out  = (const float*)d_in[12];
    const float* b_out  = (const float*)d_in[13];
    const float* Wg     = (const float*)d_in[14];
    const float* bg     = (const float*)d_in[15];
    const float* Wv     = (const float*)d_in[16];
    const float* bv     = (const float*)d_in[17];
    float* out = (float*)d_out;

    // ---- workspace ----
    float* ws = (float*)d_ws;
    size_t off = 0;
    float* xp    = ws + off; off += (size_t)MROWS * DI;        // 4M f
    float* xpc   = ws + off; off += (size_t)MROWS * DI;        // 4M f
    float* dblf  = ws + off; off += (size_t)MROWS * 96;
    float* comb  = ws + off; off += (size_t)MROWS * 2 * DM;    // 4M f
    float* chS   = ws + off; off += (size_t)BB * NCH * DI;     // 0.25M f
    ushort_t* sbase = (ushort_t*)(ws + off);
    size_t soff = 0;
    ushort_t* xlnb   = sbase + soff; soff += (size_t)MROWS * DM;        // 2M sh
    ushort_t* zb     = sbase + soff; soff += (size_t)MROWS * DI;        // 4M sh
    ushort_t* deltab = sbase + soff; soff += (size_t)MROWS * DI;        // 4M sh
    ushort_t* ybufb  = sbase + soff; soff += (size_t)MROWS * DI;        // 4M sh
    ushort_t* chHb   = sbase + soff; soff += (size_t)BB * NCH * DI * NS;// 4M sh
    ushort_t* WTin   = sbase + soff; soff += (size_t)(2 * DI) * DM;     // 4M sh
    ushort_t* WTout  = sbase + soff; soff += (size_t)2 * DM * DI;       // 4M sh
    ushort_t* WTgv   = sbase + soff; soff += (size_t)2 * DM * (2 * DM); // 4M sh
    ushort_t* xpcb   = sbase + soff; soff += (size_t)MROWS * DI;        // 4M sh
    ushort_t* dtb    = sbase + soff; soff += (size_t)MROWS * RR;        // 0.125M sh
    ushort_t* WTxp   = sbase + soff; soff += (size_t)2 * 96 * DI;       // 0.375M sh
    ushort_t* WTdt   = sbase + soff; soff += (size_t)2 * DI * RR;       // 0.25M sh
    // split-K partial buffer: aliases deltab+ybufb (dead during xproj/reduce)
    float* part = (float*)deltab;   // NSPLIT*MROWS*96 f32 = 12.6 MB <= 16 MB region

    // ---- one-time weight transforms ----
    tcast<<<dim3(DM / 64, DI / 64, 2), 256, 0, stream>>>(
        W_out, (long)DI * DM, WTout, (long)DM * DI, DI, DM);
    tcast<<<dim3(DM / 64, (2 * DM) / 64, 1), 256, 0, stream>>>(
        Wg, 0, WTgv, 0, 2 * DM, DM);
    tcast<<<dim3(DM / 64, (2 * DM) / 64, 1), 256, 0, stream>>>(
        Wv, 0, WTgv + (size_t)DM * 2 * DM, 0, 2 * DM, DM);
    // W_dt [2][RR][DI] -> WTdt [2][DI][RR]
    tcast<<<dim3(DI / 64, RR / 64, 2), 256, 0, stream>>>(
        W_dt, (long)RR * DI, WTdt, (long)DI * RR, RR, DI);
    // W_xproj [2][DI][96] -> WTxp [2][96][DI]
    tcastP<<<dim3((DI * 96 + 255) / 256, 1, 2), 256, 0, stream>>>(
        W_xproj, (long)DI * 96, WTxp, (long)96 * DI, DI, 96);

    for (int d = 0; d < 2; ++d) {
        const float* Alg = A_log + (size_t)d * DI * NS;
        // W_in[d] [DM][2DI] -> WTin [2DI][DM]
        tcast<<<dim3((2 * DI) / 64, DM / 64, 1), 256, 0, stream>>>(
            W_in + (size_t)d * DM * 2 * DI, 0, WTin, 0, DM, 2 * DI);
        ln_kernel<<<MROWS, 256, 0, stream>>>(
            x, ln_w + (size_t)d * DM, ln_b + (size_t)d * DM, xlnb);
        // xz = xln @ W_in + b_in
        gemm_bf<EPI_XPZ><<<dim3((2 * DI) / 128, MROWS / 128), 256, 0, stream>>>(
            xlnb, DM, WTin, DM, b_in + (size_t)d * 2 * DI,
            xp, DI, zb, DI, nullptr, 0, DM);
        conv_silu_kernel<<<(MROWS * DI) / 256, 256, 0, stream>>>(
            xp, conv_w + (size_t)d * DI * 4, conv_b + (size_t)d * DI, xpc, xpcb, d);
        // dbl = xpc @ W_xproj  (split-K MFMA + reduce)
        gemm_xproj<<<dim3(NSPLIT, MROWS / 128), 256, 0, stream>>>(
            xpcb, WTxp + (size_t)d * 96 * DI, part);
        dbl_reduce<<<(MROWS * 96) / 256, 256, 0, stream>>>(part, dblf, dtb);
        // delta = softplus(dt @ W_dt + b_dt) -> bf16
        gemm_bf<EPI_SOFT><<<dim3(DI / 128, MROWS / 128), 256, 0, stream>>>(
            dtb, RR, WTdt + (size_t)d * DI * RR, RR, b_dt + (size_t)d * DI,
            nullptr, 0, deltab, DI, nullptr, 0, RR);
        // chunked scan
        scan_part1<<<dim3(DI / 256, NCH, BB), 256, 0, stream>>>(
            deltab, xpc, dblf, Alg, chS, chHb, d);
        scan_part2<<<(BB * DI * NS) / 256, 256, 0, stream>>>(chHb, chS, Alg);
        scan_part3<<<dim3(DI / 256, NCH, BB), 256, 0, stream>>>(
            deltab, xpc, dblf, zb, Alg, Dp + (size_t)d * DI, chHb, ybufb, d);
        // comb[:, d*DM:] = x + ybuf @ W_out + b_out
        gemm_bf<EPI_COMB><<<dim3(DM / 128, MROWS / 128), 256, 0, stream>>>(
            ybufb, DI, WTout + (size_t)d * DM * DI, DI, b_out + (size_t)d * DM,
            comb + (size_t)d * DM, 2 * DM, nullptr, 0, x, DM, DI);
    }

    gemm_final<<<dim3(DM / 128, MROWS / 128), 256, 0, stream>>>(
        comb, 2 * DM, WTgv, WTgv + (size_t)DM * 2 * DM, 2 * DM, bg, bv, out);
}

// Round 5
// 556.937 us; speedup vs baseline: 5.6687x; 1.2436x over previous
//
#include <hip/hip_runtime.h>
#include <math.h>

constexpr int BB = 2;
constexpr int LL = 1024;
constexpr int DM = 1024;
constexpr int DI = 2048;
constexpr int NS = 16;
constexpr int RR = 64;
constexpr int MROWS = BB * LL;

constexpr int CLEN = 16;
constexpr int NCH = LL / CLEN;  // 64

constexpr int LDT = 40;         // padded LDS stride for gemm_xproj

constexpr int NSPLIT = 16;      // split-K slices for xproj
constexpr int KCH = DI / NSPLIT; // 128

#define DEV __device__ __forceinline__

typedef unsigned short ushort_t;
using bf16x8 = __attribute__((ext_vector_type(8))) short;
using f32x4  = __attribute__((ext_vector_type(4))) float;

DEV float sigmoidf_(float x) { return 1.f / (1.f + expf(-x)); }
DEV float siluf_(float x) { return x * sigmoidf_(x); }
DEV float softplusf_(float x) { return (x > 20.f) ? x : log1pf(expf(x)); }

DEV ushort_t f2bf(float x) {
    union { float f; unsigned u; } v; v.f = x;
    unsigned r = v.u + 0x7FFFu + ((v.u >> 16) & 1u);
    return (ushort_t)(r >> 16);
}
DEV float bf2f(ushort_t u) {
    union { unsigned u; float f; } v; v.u = ((unsigned)u) << 16;
    return v.f;
}

// async global->LDS, 16B per lane; LDS dest = wave-uniform base + lane*16
typedef const __attribute__((address_space(1))) unsigned int* gptr_t;
typedef __attribute__((address_space(3))) unsigned int* lptr_t;
DEV void gload16(const void* g, void* l) {
    __builtin_amdgcn_global_load_lds((gptr_t)g, (lptr_t)l, 16, 0, 0);
}

// ---------------------------------------------------------------------------
// Transpose-cast: fp32 [R][C] -> bf16 [C][R]. 64x64 tiles.
// ---------------------------------------------------------------------------
__global__ __launch_bounds__(256) void tcast(
    const float* __restrict__ in, long sIn,
    ushort_t* __restrict__ outT, long sOut,
    int R, int C)
{
    in += (size_t)blockIdx.z * sIn;
    outT += (size_t)blockIdx.z * sOut;
    __shared__ float tile[64][65];
    int r0 = blockIdx.y * 64, c0 = blockIdx.x * 64;
#pragma unroll
    for (int i = 0; i < 4; ++i) {
        int r = (threadIdx.x >> 4) + i * 16;
        int c4 = (threadIdx.x & 15) * 4;
        float4 v = *reinterpret_cast<const float4*>(&in[(size_t)(r0 + r) * C + c0 + c4]);
        tile[r][c4] = v.x; tile[r][c4 + 1] = v.y; tile[r][c4 + 2] = v.z; tile[r][c4 + 3] = v.w;
    }
    __syncthreads();
#pragma unroll
    for (int i = 0; i < 2; ++i) {
        int c = (threadIdx.x >> 3) + i * 32;
        int r8 = (threadIdx.x & 7) * 8;
        ushort_t o[8];
#pragma unroll
        for (int j = 0; j < 8; ++j) o[j] = f2bf(tile[r8 + j][c]);
        *reinterpret_cast<int4*>(&outT[(size_t)(c0 + c) * R + r0 + r8]) =
            *reinterpret_cast<int4*>(o);
    }
}

// Guarded scalar transpose-cast (W_xproj [DI][96] -> [96][DI]).
__global__ __launch_bounds__(256) void tcastP(
    const float* __restrict__ in, long sIn,
    ushort_t* __restrict__ outT, long sOut,
    int R, int C)
{
    in += (size_t)blockIdx.z * sIn;
    outT += (size_t)blockIdx.z * sOut;
    int idx = blockIdx.x * 256 + threadIdx.x;
    if (idx >= R * C) return;
    int r = idx / C, c = idx - r * C;
    outT[(size_t)c * R + r] = f2bf(in[idx]);
}

// ---------------------------------------------------------------------------
// LayerNorm (one direction) -> bf16
// ---------------------------------------------------------------------------
__global__ __launch_bounds__(256) void ln_kernel(
    const float* __restrict__ x,
    const float* __restrict__ ln_w,
    const float* __restrict__ ln_b,
    ushort_t* __restrict__ xlnb)
{
    int row = blockIdx.x;
    const float* xr = x + (size_t)row * DM;
    int i4 = threadIdx.x * 4;
    float4 v = *reinterpret_cast<const float4*>(&xr[i4]);
    float s = v.x + v.y + v.z + v.w;
    float s2 = v.x * v.x + v.y * v.y + v.z * v.z + v.w * v.w;
    for (int off = 32; off > 0; off >>= 1) {
        s += __shfl_down(s, off);
        s2 += __shfl_down(s2, off);
    }
    __shared__ float sbuf[10];
    int wid = threadIdx.x >> 6;
    if ((threadIdx.x & 63) == 0) { sbuf[wid] = s; sbuf[4 + wid] = s2; }
    __syncthreads();
    if (threadIdx.x == 0) {
        float S = sbuf[0] + sbuf[1] + sbuf[2] + sbuf[3];
        float S2 = sbuf[4] + sbuf[5] + sbuf[6] + sbuf[7];
        float mu = S / DM;
        float var = S2 / DM - mu * mu;
        sbuf[8] = mu;
        sbuf[9] = rsqrtf(var + 1e-5f);
    }
    __syncthreads();
    float mu = sbuf[8], rstd = sbuf[9];
    float4 w = *reinterpret_cast<const float4*>(&ln_w[i4]);
    float4 b = *reinterpret_cast<const float4*>(&ln_b[i4]);
    ushort_t o[4];
    o[0] = f2bf((v.x - mu) * rstd * w.x + b.x);
    o[1] = f2bf((v.y - mu) * rstd * w.y + b.y);
    o[2] = f2bf((v.z - mu) * rstd * w.z + b.z);
    o[3] = f2bf((v.w - mu) * rstd * w.w + b.w);
    *reinterpret_cast<uint2*>(&xlnb[(size_t)row * DM + i4]) = *reinterpret_cast<uint2*>(o);
}

// ---------------------------------------------------------------------------
// Async-staged bf16 MFMA GEMM. Tile BM x 128, BK=64, 4 waves (2x2).
// LDS linear (global_load_lds) with XOR swizzle: LDS slot s of row r holds
// global 16B-chunk (s ^ (r&7)); ds_read uses slot (lkk ^ (row&7)).
// ---------------------------------------------------------------------------
enum { EPI_XPZ = 0, EPI_COMB = 1, EPI_SOFT = 2 };

template <int BM, int EPI>
__global__ __launch_bounds__(256) void gemm_as(
    const ushort_t* __restrict__ A, int lda, long sA,
    const ushort_t* __restrict__ Bt, int ldb, long sB,
    const float* __restrict__ bias, long sBias,
    float* __restrict__ outF,
    ushort_t* __restrict__ outB,
    ushort_t* __restrict__ outB2,
    const float* __restrict__ res,
    long sOut, int Kdim)
{
    constexpr int FM = BM / 32;     // M frags per wave
    constexpr int CA = BM / 8;      // A chunks (1KB each)
    constexpr int CT = CA + 16;     // total chunks
    __shared__ ushort_t As[BM * 64];
    __shared__ ushort_t Bs[128 * 64];

    int z = blockIdx.z;
    A += (size_t)z * sA; Bt += (size_t)z * sB; bias += (size_t)z * sBias;
    outF += (size_t)z * sOut; outB += (size_t)z * sOut;

    int tid = threadIdx.x;
    int lane = tid & 63;
    int w = tid >> 6, wr = w >> 1, wc = w & 1;
    int lrow = lane & 15, lk = lane >> 4;
    int cr = lane >> 3, cs = lane & 7;
    int row0 = blockIdx.y * BM, col0 = blockIdx.x * 128;

    f32x4 acc[FM][4];
#pragma unroll
    for (int m = 0; m < FM; ++m)
#pragma unroll
        for (int n = 0; n < 4; ++n) acc[m][n] = {0.f, 0.f, 0.f, 0.f};

    for (int k0 = 0; k0 < Kdim; k0 += 64) {
#pragma unroll
        for (int j = 0; j < CT / 4; ++j) {
            int c = j * 4 + w;
            if (c < CA) {
                int r = c * 8 + cr;
                gload16(&A[(size_t)(row0 + r) * lda + k0 + ((cs ^ (r & 7)) * 8)],
                        &As[c * 512]);
            } else {
                int r = (c - CA) * 8 + cr;
                gload16(&Bt[(size_t)(col0 + r) * ldb + k0 + ((cs ^ (r & 7)) * 8)],
                        &Bs[(c - CA) * 512]);
            }
        }
        __syncthreads();   // drains vmcnt before ds_read
#pragma unroll
        for (int kk = 0; kk < 2; ++kk) {
            int lkk = kk * 4 + lk;
            bf16x8 af[FM], bfr[4];
#pragma unroll
            for (int m = 0; m < FM; ++m) {
                int ar = wr * (BM / 2) + m * 16 + lrow;
                af[m] = *reinterpret_cast<const bf16x8*>(&As[ar * 64 + ((lkk ^ (ar & 7)) * 8)]);
            }
#pragma unroll
            for (int n = 0; n < 4; ++n) {
                int br = wc * 64 + n * 16 + lrow;
                bfr[n] = *reinterpret_cast<const bf16x8*>(&Bs[br * 64 + ((lkk ^ (br & 7)) * 8)]);
            }
#pragma unroll
            for (int m = 0; m < FM; ++m)
#pragma unroll
                for (int n = 0; n < 4; ++n)
                    acc[m][n] = __builtin_amdgcn_mfma_f32_16x16x32_bf16(af[m], bfr[n], acc[m][n], 0, 0, 0);
        }
        __syncthreads();   // protect LDS before next stage
    }

#pragma unroll
    for (int n = 0; n < 4; ++n) {
        int col = col0 + wc * 64 + n * 16 + lrow;
        float bv = bias[col];
#pragma unroll
        for (int m = 0; m < FM; ++m) {
#pragma unroll
            for (int rr = 0; rr < 4; ++rr) {
                int row = row0 + wr * (BM / 2) + m * 16 + lk * 4 + rr;
                float v = acc[m][n][rr] + bv;
                if constexpr (EPI == EPI_XPZ) {
                    if (col < DI) outB[(size_t)row * DI + col] = f2bf(v);
                    else outB2[(size_t)row * DI + (col - DI)] = f2bf(v);
                } else if constexpr (EPI == EPI_COMB) {
                    v += res[(size_t)row * DM + col];
                    outF[(size_t)row * (2 * DM) + col] = v;
                    outB[(size_t)row * (2 * DM) + col] = f2bf(v);
                } else {
                    outB[(size_t)row * DI + col] = f2bf(softplusf_(v));
                }
            }
        }
    }
}

// ---------------------------------------------------------------------------
// Final fused GEMM (async-staged, BM=64): dual-B (Wg, Wv), A = combb bf16.
// ---------------------------------------------------------------------------
__global__ __launch_bounds__(256) void gemm_final_as(
    const ushort_t* __restrict__ Ab,    // combb [MROWS][2DM]
    const float* __restrict__ comb,     // fp32 for epilogue f,w
    const ushort_t* __restrict__ Bg,    // [DM][2DM]
    const ushort_t* __restrict__ Bv,
    const float* __restrict__ bgp, const float* __restrict__ bvp,
    float* __restrict__ out)
{
    __shared__ ushort_t As[64 * 64];
    __shared__ ushort_t Bs1[128 * 64];
    __shared__ ushort_t Bs2[128 * 64];
    int tid = threadIdx.x;
    int lane = tid & 63;
    int w = tid >> 6, wr = w >> 1, wc = w & 1;
    int lrow = lane & 15, lk = lane >> 4;
    int cr = lane >> 3, cs = lane & 7;
    int row0 = blockIdx.y * 64, col0 = blockIdx.x * 128;

    f32x4 accg[2][4], accv[2][4];
#pragma unroll
    for (int m = 0; m < 2; ++m)
#pragma unroll
        for (int n = 0; n < 4; ++n) { accg[m][n] = {0.f,0.f,0.f,0.f}; accv[m][n] = {0.f,0.f,0.f,0.f}; }

    for (int k0 = 0; k0 < 2 * DM; k0 += 64) {
#pragma unroll
        for (int j = 0; j < 10; ++j) {
            int c = j * 4 + w;
            if (c < 8) {
                int r = c * 8 + cr;
                gload16(&Ab[(size_t)(row0 + r) * (2 * DM) + k0 + ((cs ^ (r & 7)) * 8)],
                        &As[c * 512]);
            } else if (c < 24) {
                int r = (c - 8) * 8 + cr;
                gload16(&Bg[(size_t)(col0 + r) * (2 * DM) + k0 + ((cs ^ (r & 7)) * 8)],
                        &Bs1[(c - 8) * 512]);
            } else {
                int r = (c - 24) * 8 + cr;
                gload16(&Bv[(size_t)(col0 + r) * (2 * DM) + k0 + ((cs ^ (r & 7)) * 8)],
                        &Bs2[(c - 24) * 512]);
            }
        }
        __syncthreads();
#pragma unroll
        for (int kk = 0; kk < 2; ++kk) {
            int lkk = kk * 4 + lk;
            bf16x8 af[2], b1[4], b2[4];
#pragma unroll
            for (int m = 0; m < 2; ++m) {
                int ar = wr * 32 + m * 16 + lrow;
                af[m] = *reinterpret_cast<const bf16x8*>(&As[ar * 64 + ((lkk ^ (ar & 7)) * 8)]);
            }
#pragma unroll
            for (int n = 0; n < 4; ++n) {
                int br = wc * 64 + n * 16 + lrow;
                b1[n] = *reinterpret_cast<const bf16x8*>(&Bs1[br * 64 + ((lkk ^ (br & 7)) * 8)]);
                b2[n] = *reinterpret_cast<const bf16x8*>(&Bs2[br * 64 + ((lkk ^ (br & 7)) * 8)]);
            }
#pragma unroll
            for (int m = 0; m < 2; ++m)
#pragma unroll
                for (int n = 0; n < 4; ++n) {
                    accg[m][n] = __builtin_amdgcn_mfma_f32_16x16x32_bf16(af[m], b1[n], accg[m][n], 0, 0, 0);
                    accv[m][n] = __builtin_amdgcn_mfma_f32_16x16x32_bf16(af[m], b2[n], accv[m][n], 0, 0, 0);
                }
        }
        __syncthreads();
    }

#pragma unroll
    for (int n = 0; n < 4; ++n) {
        int col = col0 + wc * 64 + n * 16 + lrow;
        float bgv = bgp[col];
        float bvv = bvp[col];
#pragma unroll
        for (int m = 0; m < 2; ++m) {
#pragma unroll
            for (int rr = 0; rr < 4; ++rr) {
                int row = row0 + wr * 32 + m * 16 + lk * 4 + rr;
                float g = sigmoidf_(accg[m][n][rr] + bgv);
                float v = accv[m][n][rr] + bvv;
                float f = comb[(size_t)row * (2 * DM) + col];
                float wv2 = comb[(size_t)row * (2 * DM) + DM + col];
                out[(size_t)row * DM + col] = 0.5f * (g * v + (1.f - g) * (f + wv2));
            }
        }
    }
}

// ---------------------------------------------------------------------------
// Split-K MFMA GEMM for xproj (reg-staged, padded LDS; small and fast enough)
// ---------------------------------------------------------------------------
__global__ __launch_bounds__(256) void gemm_xproj(
    const ushort_t* __restrict__ A,
    const ushort_t* __restrict__ Bt,
    float* __restrict__ part)         // [NSPLIT][MROWS][96]
{
    __shared__ ushort_t As[128 * LDT];
    __shared__ ushort_t Bs[96 * LDT];
    int tid = threadIdx.x;
    int lane = tid & 63;
    int w = tid >> 6, wr = w >> 1, wc = w & 1;
    int lrow = lane & 15, lk = lane >> 4;
    int s = blockIdx.x, rt = blockIdx.y;
    int row0 = rt * 128;
    int k0 = s * KCH;

    f32x4 acc[4][3];
#pragma unroll
    for (int m = 0; m < 4; ++m)
#pragma unroll
        for (int n = 0; n < 3; ++n) acc[m][n] = {0.f, 0.f, 0.f, 0.f};

    int sr = tid >> 2, ss = tid & 3;
    const ushort_t* ga0 = A + (size_t)(row0 + sr) * DI + k0 + ss * 8;
    const ushort_t* ga1 = A + (size_t)(row0 + sr + 64) * DI + k0 + ss * 8;

    for (int kk = 0; kk < KCH; kk += 32) {
        int4 a0 = *reinterpret_cast<const int4*>(ga0);
        int4 a1 = *reinterpret_cast<const int4*>(ga1);
        ga0 += 32; ga1 += 32;
        __syncthreads();
        *reinterpret_cast<int4*>(&As[sr * LDT + ss * 8]) = a0;
        *reinterpret_cast<int4*>(&As[(sr + 64) * LDT + ss * 8]) = a1;
        for (int i = tid; i < 96 * 4; i += 256) {
            int br = i >> 2, bs = i & 3;
            *reinterpret_cast<int4*>(&Bs[br * LDT + bs * 8]) =
                *reinterpret_cast<const int4*>(&Bt[(size_t)br * DI + k0 + kk + bs * 8]);
        }
        __syncthreads();
        bf16x8 af[4], bfr[3];
#pragma unroll
        for (int m = 0; m < 4; ++m)
            af[m] = *reinterpret_cast<const bf16x8*>(&As[(wr * 64 + m * 16 + lrow) * LDT + lk * 8]);
#pragma unroll
        for (int n = 0; n < 3; ++n)
            bfr[n] = *reinterpret_cast<const bf16x8*>(&Bs[(wc * 48 + n * 16 + lrow) * LDT + lk * 8]);
#pragma unroll
        for (int m = 0; m < 4; ++m)
#pragma unroll
            for (int n = 0; n < 3; ++n)
                acc[m][n] = __builtin_amdgcn_mfma_f32_16x16x32_bf16(af[m], bfr[n], acc[m][n], 0, 0, 0);
    }

#pragma unroll
    for (int n = 0; n < 3; ++n) {
        int col = wc * 48 + n * 16 + lrow;
#pragma unroll
        for (int m = 0; m < 4; ++m) {
#pragma unroll
            for (int rr = 0; rr < 4; ++rr) {
                int row = row0 + wr * 64 + m * 16 + lk * 4 + rr;
                part[((size_t)s * MROWS + row) * 96 + col] = acc[m][n][rr];
            }
        }
    }
}

__global__ __launch_bounds__(256) void dbl_reduce(
    const float* __restrict__ part,
    float* __restrict__ dblf,
    ushort_t* __restrict__ dtb)
{
    int idx = blockIdx.x * 256 + threadIdx.x;   // MROWS*96
    int row = idx / 96, col = idx - row * 96;
    float v = 0.f;
#pragma unroll
    for (int s = 0; s < NSPLIT; ++s)
        v += part[((size_t)s * MROWS + row) * 96 + col];
    dblf[idx] = v;
    if (col < RR) dtb[(size_t)row * RR + col] = f2bf(v);
}

// ---------------------------------------------------------------------------
// Depthwise conv K=4 + SiLU, bf16 in/out
// ---------------------------------------------------------------------------
__global__ __launch_bounds__(256) void conv_silu_kernel(
    const ushort_t* __restrict__ xpb,   // [MROWS][DI] bf16
    const float* __restrict__ cw,
    const float* __restrict__ cb,
    ushort_t* __restrict__ xpcb,
    int reverse)
{
    int idx = blockIdx.x * 256 + threadIdx.x;
    int c = idx & (DI - 1);
    int row = idx >> 11;
    int t = row & (LL - 1);
    int b = row >> 10;
    float w0 = cw[c * 4 + 0], w1 = cw[c * 4 + 1], w2 = cw[c * 4 + 2], w3 = cw[c * 4 + 3];
    float acc = cb[c];
    if (!reverse) {
#pragma unroll
        for (int k = 0; k < 4; ++k) {
            int tt = t - 3 + k;
            if (tt >= 0) {
                float wv = (k == 0) ? w0 : (k == 1) ? w1 : (k == 2) ? w2 : w3;
                acc = fmaf(wv, bf2f(xpb[(size_t)(b * LL + tt) * DI + c]), acc);
            }
        }
    } else {
#pragma unroll
        for (int k = 0; k < 4; ++k) {
            int tt = t + 3 - k;
            if (tt < LL) {
                float wv = (k == 0) ? w0 : (k == 1) ? w1 : (k == 2) ? w2 : w3;
                acc = fmaf(wv, bf2f(xpb[(size_t)(b * LL + tt) * DI + c]), acc);
            }
        }
    }
    xpcb[idx] = f2bf(siluf_(acc));
}

// ---------------------------------------------------------------------------
// Chunked scan
// ---------------------------------------------------------------------------
__global__ __launch_bounds__(256) void scan_part1(
    const ushort_t* __restrict__ delta_b,
    const ushort_t* __restrict__ xpcb,
    const float* __restrict__ dbl,
    const float* __restrict__ A_log,
    float* __restrict__ chunkS,
    ushort_t* __restrict__ chunkH,
    int reverse)
{
    int c = blockIdx.x * 256 + threadIdx.x;
    int ch = blockIdx.y;
    int b = blockIdx.z;
    int base = b * LL;

    __shared__ float sB[CLEN][16];
    {
        int r = threadIdx.x >> 4;
        int col = threadIdx.x & 15;
        int i = ch * CLEN + r;
        int t = reverse ? (LL - 1 - i) : i;
        sB[r][col] = dbl[(size_t)(base + t) * 96 + RR + col];
    }
    __syncthreads();

    float Ac[NS];
#pragma unroll
    for (int q = 0; q < 4; ++q) {
        float4 a = *reinterpret_cast<const float4*>(&A_log[(size_t)c * NS + q * 4]);
        Ac[q * 4 + 0] = -__expf(a.x);
        Ac[q * 4 + 1] = -__expf(a.y);
        Ac[q * 4 + 2] = -__expf(a.z);
        Ac[q * 4 + 3] = -__expf(a.w);
    }
    float h[NS] = {};
    float S = 0.f;
#pragma unroll
    for (int ii = 0; ii < CLEN; ++ii) {
        int i = ch * CLEN + ii;
        int t = reverse ? (LL - 1 - i) : i;
        size_t row = (size_t)(base + t);
        float dlt = bf2f(delta_b[row * DI + c]);
        float xv = bf2f(xpcb[row * DI + c]);
        S += dlt;
        float dx = dlt * xv;
        float4 B0 = *reinterpret_cast<const float4*>(&sB[ii][0]);
        float4 B1 = *reinterpret_cast<const float4*>(&sB[ii][4]);
        float4 B2 = *reinterpret_cast<const float4*>(&sB[ii][8]);
        float4 B3 = *reinterpret_cast<const float4*>(&sB[ii][12]);
        float Bv[NS] = {B0.x, B0.y, B0.z, B0.w, B1.x, B1.y, B1.z, B1.w,
                        B2.x, B2.y, B2.z, B2.w, B3.x, B3.y, B3.z, B3.w};
#pragma unroll
        for (int n = 0; n < NS; ++n)
            h[n] = fmaf(__expf(dlt * Ac[n]), h[n], dx * Bv[n]);
    }
    size_t sidx = ((size_t)(b * NCH + ch)) * DI + c;
    chunkS[sidx] = S;
    ushort_t o[16];
#pragma unroll
    for (int n = 0; n < NS; ++n) o[n] = f2bf(h[n]);
    ushort_t* hp = chunkH + sidx * NS;
    *reinterpret_cast<int4*>(&hp[0]) = *reinterpret_cast<int4*>(&o[0]);
    *reinterpret_cast<int4*>(&hp[8]) = *reinterpret_cast<int4*>(&o[8]);
}

__global__ __launch_bounds__(256) void scan_part2(
    ushort_t* __restrict__ chunkH,
    const float* __restrict__ chunkS,
    const float* __restrict__ A_log)
{
    int idx = blockIdx.x * 256 + threadIdx.x;
    int n = idx & 15;
    int c = (idx >> 4) & (DI - 1);
    int b = idx >> 15;
    float Ac = -__expf(A_log[(size_t)c * NS + n]);
    float cur = 0.f;
    for (int j = 0; j < NCH; ++j) {
        size_t sidx = ((size_t)(b * NCH + j)) * DI + c;
        float S = chunkS[sidx];
        float hf = bf2f(chunkH[sidx * NS + n]);
        float nxt = fmaf(__expf(Ac * S), cur, hf);
        chunkH[sidx * NS + n] = f2bf(cur);
        cur = nxt;
    }
}

__global__ __launch_bounds__(256) void scan_part3(
    const ushort_t* __restrict__ delta_b,
    const ushort_t* __restrict__ xpcb,
    const float* __restrict__ dbl,
    const ushort_t* __restrict__ zb,
    const float* __restrict__ A_log,
    const float* __restrict__ Dp,
    const ushort_t* __restrict__ chunkH,
    ushort_t* __restrict__ ybufb,
    int reverse)
{
    int c = blockIdx.x * 256 + threadIdx.x;
    int ch = blockIdx.y;
    int b = blockIdx.z;
    int base = b * LL;

    __shared__ float sBC[CLEN][32];
    for (int r = threadIdx.x >> 5; r < CLEN; r += 8) {
        int col = threadIdx.x & 31;
        int i = ch * CLEN + r;
        int t = reverse ? (LL - 1 - i) : i;
        sBC[r][col] = dbl[(size_t)(base + t) * 96 + RR + col];
    }
    __syncthreads();

    float Ac[NS];
#pragma unroll
    for (int q = 0; q < 4; ++q) {
        float4 a = *reinterpret_cast<const float4*>(&A_log[(size_t)c * NS + q * 4]);
        Ac[q * 4 + 0] = -__expf(a.x);
        Ac[q * 4 + 1] = -__expf(a.y);
        Ac[q * 4 + 2] = -__expf(a.z);
        Ac[q * 4 + 3] = -__expf(a.w);
    }
    size_t sidx = ((size_t)(b * NCH + ch)) * DI + c;
    const ushort_t* hp = chunkH + sidx * NS;
    int4 h0 = *reinterpret_cast<const int4*>(&hp[0]);
    int4 h1 = *reinterpret_cast<const int4*>(&hp[8]);
    const ushort_t* hs0 = reinterpret_cast<const ushort_t*>(&h0);
    const ushort_t* hs1 = reinterpret_cast<const ushort_t*>(&h1);
    float h[NS];
#pragma unroll
    for (int n = 0; n < 8; ++n) { h[n] = bf2f(hs0[n]); h[8 + n] = bf2f(hs1[n]); }
    float Dc = Dp[c];
#pragma unroll
    for (int ii = 0; ii < CLEN; ++ii) {
        int i = ch * CLEN + ii;
        int t = reverse ? (LL - 1 - i) : i;
        size_t row = (size_t)(base + t);
        float dlt = bf2f(delta_b[row * DI + c]);
        float xv = bf2f(xpcb[row * DI + c]);
        float dx = dlt * xv;
        float4 B0 = *reinterpret_cast<const float4*>(&sBC[ii][0]);
        float4 B1 = *reinterpret_cast<const float4*>(&sBC[ii][4]);
        float4 B2 = *reinterpret_cast<const float4*>(&sBC[ii][8]);
        float4 B3 = *reinterpret_cast<const float4*>(&sBC[ii][12]);
        float4 C0 = *reinterpret_cast<const float4*>(&sBC[ii][16]);
        float4 C1 = *reinterpret_cast<const float4*>(&sBC[ii][20]);
        float4 C2 = *reinterpret_cast<const float4*>(&sBC[ii][24]);
        float4 C3 = *reinterpret_cast<const float4*>(&sBC[ii][28]);
        float Bv[NS] = {B0.x, B0.y, B0.z, B0.w, B1.x, B1.y, B1.z, B1.w,
                        B2.x, B2.y, B2.z, B2.w, B3.x, B3.y, B3.z, B3.w};
        float Cv[NS] = {C0.x, C0.y, C0.z, C0.w, C1.x, C1.y, C1.z, C1.w,
                        C2.x, C2.y, C2.z, C2.w, C3.x, C3.y, C3.z, C3.w};
        float y = 0.f;
#pragma unroll
        for (int n = 0; n < NS; ++n) {
            h[n] = fmaf(__expf(dlt * Ac[n]), h[n], dx * Bv[n]);
            y = fmaf(h[n], Cv[n], y);
        }
        float z = bf2f(zb[row * DI + c]);
        ybufb[row * DI + c] = f2bf((y + xv * Dc) * siluf_(z));
    }
}

// ---------------------------------------------------------------------------
extern "C" void kernel_launch(void* const* d_in, const int* in_sizes, int n_in,
                              void* d_out, int out_size, void* d_ws, size_t ws_size,
                              hipStream_t stream)
{
    const float* x      = (const float*)d_in[0];
    const float* ln_w   = (const float*)d_in[1];
    const float* ln_b   = (const float*)d_in[2];
    const float* W_in   = (const float*)d_in[3];
    const float* b_in   = (const float*)d_in[4];
    const float* conv_w = (const float*)d_in[5];
    const float* conv_b = (const float*)d_in[6];
    const float* W_xproj= (const float*)d_in[7];
    const float* W_dt   = (const float*)d_in[8];
    const float* b_dt   = (const float*)d_in[9];
    const float* A_log  = (const float*)d_in[10];
    const float* Dp     = (const float*)d_in[11];
    const float* W_out  = (const float*)d_in[12];
    const float* b_out  = (const float*)d_in[13];
    const float* Wg     = (const float*)d_in[14];
    const float* bg     = (const float*)d_in[15];
    const float* Wv     = (const float*)d_in[16];
    const float* bv     = (const float*)d_in[17];
    float* out = (float*)d_out;

    // ---- workspace (~111 MB total) ----
    float* ws = (float*)d_ws;
    size_t off = 0;
    float* dblf  = ws + off; off += (size_t)MROWS * 96;        // 0.75 MB
    float* comb  = ws + off; off += (size_t)MROWS * 2 * DM;    // 16 MB
    float* chS   = ws + off; off += (size_t)BB * NCH * DI;     // 1 MB
    ushort_t* sbase = (ushort_t*)(ws + off);
    size_t soff = 0;
    ushort_t* xlnb   = sbase + soff; soff += (size_t)MROWS * DM;            // 4 MB
    ushort_t* xpb    = sbase + soff; soff += (size_t)MROWS * DI;            // 8 MB
    ushort_t* zb     = sbase + soff; soff += (size_t)MROWS * DI;            // 8 MB
    ushort_t* xpcb   = sbase + soff; soff += (size_t)MROWS * DI;            // 8 MB
    ushort_t* deltab = sbase + soff; soff += (size_t)2 * MROWS * DI;        // 16 MB (2 dirs)
    ushort_t* ybufb  = sbase + soff; soff += (size_t)2 * MROWS * DI;        // 16 MB (2 dirs)
    ushort_t* chHb   = sbase + soff; soff += (size_t)BB * NCH * DI * NS;    // 8 MB
    ushort_t* combb  = sbase + soff; soff += (size_t)MROWS * 2 * DM;        // 8 MB
    ushort_t* dtb    = sbase + soff; soff += (size_t)MROWS * RR;            // 0.25 MB
    ushort_t* WTin   = sbase + soff; soff += (size_t)(2 * DI) * DM;         // 8 MB
    ushort_t* WTout  = sbase + soff; soff += (size_t)2 * DM * DI;           // 8 MB
    ushort_t* WTgv   = sbase + soff; soff += (size_t)2 * DM * (2 * DM);     // 8 MB
    ushort_t* WTxp   = sbase + soff; soff += (size_t)2 * 96 * DI;           // 0.75 MB
    ushort_t* WTdt   = sbase + soff; soff += (size_t)2 * DI * RR;           // 0.5 MB
    // split-K partials alias the deltab[2] region (dead during xproj/reduce)
    float* part = (float*)deltab;   // 16*2048*96*4B = 12.6 MB <= 16 MB

    // ---- one-time weight transforms ----
    tcast<<<dim3(DM / 64, DI / 64, 2), 256, 0, stream>>>(
        W_out, (long)DI * DM, WTout, (long)DM * DI, DI, DM);
    tcast<<<dim3(DM / 64, (2 * DM) / 64, 1), 256, 0, stream>>>(
        Wg, 0, WTgv, 0, 2 * DM, DM);
    tcast<<<dim3(DM / 64, (2 * DM) / 64, 1), 256, 0, stream>>>(
        Wv, 0, WTgv + (size_t)DM * 2 * DM, 0, 2 * DM, DM);
    tcast<<<dim3(DI / 64, RR / 64, 2), 256, 0, stream>>>(
        W_dt, (long)RR * DI, WTdt, (long)DI * RR, RR, DI);
    tcastP<<<dim3((DI * 96 + 255) / 256, 1, 2), 256, 0, stream>>>(
        W_xproj, (long)DI * 96, WTxp, (long)96 * DI, DI, 96);

    for (int d = 0; d < 2; ++d) {
        const float* Alg = A_log + (size_t)d * DI * NS;
        ushort_t* delta_d = deltab + (size_t)d * MROWS * DI;
        ushort_t* ybuf_d  = ybufb + (size_t)d * MROWS * DI;
        tcast<<<dim3((2 * DI) / 64, DM / 64, 1), 256, 0, stream>>>(
            W_in + (size_t)d * DM * 2 * DI, 0, WTin, 0, DM, 2 * DI);
        ln_kernel<<<MROWS, 256, 0, stream>>>(
            x, ln_w + (size_t)d * DM, ln_b + (size_t)d * DM, xlnb);
        // xz = xln @ W_in + b_in  -> xpb (bf16) | zb (bf16)
        gemm_as<128, EPI_XPZ><<<dim3((2 * DI) / 128, MROWS / 128, 1), 256, 0, stream>>>(
            xlnb, DM, 0, WTin, DM, 0, b_in + (size_t)d * 2 * DI, 0,
            nullptr, xpb, zb, nullptr, 0, DM);
        conv_silu_kernel<<<(MROWS * DI) / 256, 256, 0, stream>>>(
            xpb, conv_w + (size_t)d * DI * 4, conv_b + (size_t)d * DI, xpcb, d);
        // dbl = xpc @ W_xproj (split-K + reduce)
        gemm_xproj<<<dim3(NSPLIT, MROWS / 128), 256, 0, stream>>>(
            xpcb, WTxp + (size_t)d * 96 * DI, part);
        dbl_reduce<<<(MROWS * 96) / 256, 256, 0, stream>>>(part, dblf, dtb);
        // delta = softplus(dt @ W_dt + b_dt) -> bf16
        gemm_as<128, EPI_SOFT><<<dim3(DI / 128, MROWS / 128, 1), 256, 0, stream>>>(
            dtb, RR, 0, WTdt + (size_t)d * DI * RR, RR, 0, b_dt + (size_t)d * DI, 0,
            nullptr, delta_d, nullptr, nullptr, 0, RR);
        // chunked scan -> ybuf_d
        scan_part1<<<dim3(DI / 256, NCH, BB), 256, 0, stream>>>(
            delta_d, xpcb, dblf, Alg, chS, chHb, d);
        scan_part2<<<(BB * DI * NS) / 256, 256, 0, stream>>>(chHb, chS, Alg);
        scan_part3<<<dim3(DI / 256, NCH, BB), 256, 0, stream>>>(
            delta_d, xpcb, dblf, zb, Alg, Dp + (size_t)d * DI, chHb, ybuf_d, d);
    }

    // batched COMB over both directions: comb[:, z*DM:] = x + ybuf[z] @ W_out[z] + b_out[z]
    gemm_as<64, EPI_COMB><<<dim3(DM / 128, MROWS / 64, 2), 256, 0, stream>>>(
        ybufb, DI, (long)MROWS * DI, WTout, DI, (long)DM * DI, b_out, DM,
        comb, combb, nullptr, x, DM, DI);

    // final fused dual GEMM + mix
    gemm_final_as<<<dim3(DM / 128, MROWS / 64), 256, 0, stream>>>(
        combb, comb, WTgv, WTgv + (size_t)DM * 2 * DM, bg, bv, out);
}

// Round 6
// 379.447 us; speedup vs baseline: 8.3203x; 1.4678x over previous
//
#include <hip/hip_runtime.h>
#include <math.h>

constexpr int BB = 2;
constexpr int LL = 1024;
constexpr int DM = 1024;
constexpr int DI = 2048;
constexpr int NS = 16;
constexpr int RR = 64;
constexpr int MROWS = BB * LL;

constexpr int CLEN = 32;
constexpr int NCH = LL / CLEN;  // 32

constexpr int LDT = 40;          // padded LDS stride for gemm_xproj
constexpr int NSPLIT = 16;       // split-K slices for xproj
constexpr int KCH = DI / NSPLIT; // 128

#define DEV __device__ __forceinline__

typedef unsigned short ushort_t;
using bf16x8 = __attribute__((ext_vector_type(8))) short;
using f32x4  = __attribute__((ext_vector_type(4))) float;

DEV float sigmoidf_(float x) { return 1.f / (1.f + expf(-x)); }
DEV float siluf_(float x) { return x * sigmoidf_(x); }
DEV float softplusf_(float x) { return (x > 20.f) ? x : log1pf(expf(x)); }

DEV ushort_t f2bf(float x) {
    union { float f; unsigned u; } v; v.f = x;
    unsigned r = v.u + 0x7FFFu + ((v.u >> 16) & 1u);
    return (ushort_t)(r >> 16);
}
DEV float bf2f(ushort_t u) {
    union { unsigned u; float f; } v; v.u = ((unsigned)u) << 16;
    return v.f;
}

// async global->LDS, 16B/lane; LDS dest = wave-uniform base + lane*16
typedef const __attribute__((address_space(1))) unsigned int* gptr_t;
typedef __attribute__((address_space(3))) unsigned int* lptr_t;
DEV void gload16(const void* g, void* l) {
    __builtin_amdgcn_global_load_lds((gptr_t)g, (lptr_t)l, 16, 0, 0);
}

// ---------------------------------------------------------------------------
// Transpose-cast: fp32 [R][C] -> bf16 [C][R]. 64x64 tiles.
// ---------------------------------------------------------------------------
__global__ __launch_bounds__(256) void tcast(
    const float* __restrict__ in, long sIn,
    ushort_t* __restrict__ outT, long sOut,
    int R, int C)
{
    in += (size_t)blockIdx.z * sIn;
    outT += (size_t)blockIdx.z * sOut;
    __shared__ float tile[64][65];
    int r0 = blockIdx.y * 64, c0 = blockIdx.x * 64;
#pragma unroll
    for (int i = 0; i < 4; ++i) {
        int r = (threadIdx.x >> 4) + i * 16;
        int c4 = (threadIdx.x & 15) * 4;
        float4 v = *reinterpret_cast<const float4*>(&in[(size_t)(r0 + r) * C + c0 + c4]);
        tile[r][c4] = v.x; tile[r][c4 + 1] = v.y; tile[r][c4 + 2] = v.z; tile[r][c4 + 3] = v.w;
    }
    __syncthreads();
#pragma unroll
    for (int i = 0; i < 2; ++i) {
        int c = (threadIdx.x >> 3) + i * 32;
        int r8 = (threadIdx.x & 7) * 8;
        ushort_t o[8];
#pragma unroll
        for (int j = 0; j < 8; ++j) o[j] = f2bf(tile[r8 + j][c]);
        *reinterpret_cast<int4*>(&outT[(size_t)(c0 + c) * R + r0 + r8]) =
            *reinterpret_cast<int4*>(o);
    }
}

// Guarded scalar transpose-cast (W_xproj [DI][96] -> [96][DI]).
__global__ __launch_bounds__(256) void tcastP(
    const float* __restrict__ in, long sIn,
    ushort_t* __restrict__ outT, long sOut,
    int R, int C)
{
    in += (size_t)blockIdx.z * sIn;
    outT += (size_t)blockIdx.z * sOut;
    int idx = blockIdx.x * 256 + threadIdx.x;
    if (idx >= R * C) return;
    int r = idx / C, c = idx - r * C;
    outT[(size_t)c * R + r] = f2bf(in[idx]);
}

// ---------------------------------------------------------------------------
// LayerNorm: one block per token; writes BOTH directions' bf16 outputs.
// ---------------------------------------------------------------------------
__global__ __launch_bounds__(256) void ln_kernel(
    const float* __restrict__ x,
    const float* __restrict__ ln_w,   // [2][DM]
    const float* __restrict__ ln_b,
    ushort_t* __restrict__ xlnb)      // [2][MROWS][DM]
{
    int row = blockIdx.x;
    const float* xr = x + (size_t)row * DM;
    int i4 = threadIdx.x * 4;
    float4 v = *reinterpret_cast<const float4*>(&xr[i4]);
    float s = v.x + v.y + v.z + v.w;
    float s2 = v.x * v.x + v.y * v.y + v.z * v.z + v.w * v.w;
    for (int off = 32; off > 0; off >>= 1) {
        s += __shfl_down(s, off);
        s2 += __shfl_down(s2, off);
    }
    __shared__ float sbuf[10];
    int wid = threadIdx.x >> 6;
    if ((threadIdx.x & 63) == 0) { sbuf[wid] = s; sbuf[4 + wid] = s2; }
    __syncthreads();
    if (threadIdx.x == 0) {
        float S = sbuf[0] + sbuf[1] + sbuf[2] + sbuf[3];
        float S2 = sbuf[4] + sbuf[5] + sbuf[6] + sbuf[7];
        float mu = S / DM;
        float var = S2 / DM - mu * mu;
        sbuf[8] = mu;
        sbuf[9] = rsqrtf(var + 1e-5f);
    }
    __syncthreads();
    float mu = sbuf[8], rstd = sbuf[9];
    float nv0 = (v.x - mu) * rstd, nv1 = (v.y - mu) * rstd;
    float nv2 = (v.z - mu) * rstd, nv3 = (v.w - mu) * rstd;
#pragma unroll
    for (int d = 0; d < 2; ++d) {
        float4 w = *reinterpret_cast<const float4*>(&ln_w[d * DM + i4]);
        float4 b = *reinterpret_cast<const float4*>(&ln_b[d * DM + i4]);
        ushort_t o[4];
        o[0] = f2bf(nv0 * w.x + b.x);
        o[1] = f2bf(nv1 * w.y + b.y);
        o[2] = f2bf(nv2 * w.z + b.z);
        o[3] = f2bf(nv3 * w.w + b.w);
        *reinterpret_cast<uint2*>(&xlnb[(size_t)d * MROWS * DM + (size_t)row * DM + i4]) =
            *reinterpret_cast<uint2*>(o);
    }
}

// ---------------------------------------------------------------------------
// Async-staged bf16 MFMA GEMM. Tile BM x 128, BK=64, 4 waves (2x2).
// z batched (direction). XOR-swizzled LDS via pre-swizzled global source.
// ---------------------------------------------------------------------------
enum { EPI_XPZ = 0, EPI_COMB = 1, EPI_SOFT = 2 };

template <int BM, int EPI>
__global__ __launch_bounds__(256) void gemm_as(
    const ushort_t* __restrict__ A, int lda, long sA,
    const ushort_t* __restrict__ Bt, int ldb, long sB,
    const float* __restrict__ bias, long sBias,
    ushort_t* __restrict__ outB, long sOutB,
    ushort_t* __restrict__ outB2, long sOutB2,
    const float* __restrict__ res,
    int Kdim)
{
    constexpr int FM = BM / 32;     // M frags per wave
    constexpr int CA = BM / 8;      // A chunks (1KB each)
    constexpr int CT = CA + 16;     // total chunks
    __shared__ ushort_t As[BM * 64];
    __shared__ ushort_t Bs[128 * 64];

    int z = blockIdx.z;
    A += (size_t)z * sA; Bt += (size_t)z * sB; bias += (size_t)z * sBias;
    outB += (size_t)z * sOutB;
    if (outB2) outB2 += (size_t)z * sOutB2;

    int tid = threadIdx.x;
    int lane = tid & 63;
    int w = tid >> 6, wr = w >> 1, wc = w & 1;
    int lrow = lane & 15, lk = lane >> 4;
    int cr = lane >> 3, cs = lane & 7;
    int row0 = blockIdx.y * BM, col0 = blockIdx.x * 128;

    f32x4 acc[FM][4];
#pragma unroll
    for (int m = 0; m < FM; ++m)
#pragma unroll
        for (int n = 0; n < 4; ++n) acc[m][n] = {0.f, 0.f, 0.f, 0.f};

    for (int k0 = 0; k0 < Kdim; k0 += 64) {
#pragma unroll
        for (int j = 0; j < CT / 4; ++j) {
            int c = j * 4 + w;
            if (c < CA) {
                int r = c * 8 + cr;
                gload16(&A[(size_t)(row0 + r) * lda + k0 + ((cs ^ (r & 7)) * 8)],
                        &As[c * 512]);
            } else {
                int r = (c - CA) * 8 + cr;
                gload16(&Bt[(size_t)(col0 + r) * ldb + k0 + ((cs ^ (r & 7)) * 8)],
                        &Bs[(c - CA) * 512]);
            }
        }
        __syncthreads();
#pragma unroll
        for (int kk = 0; kk < 2; ++kk) {
            int lkk = kk * 4 + lk;
            bf16x8 af[FM], bfr[4];
#pragma unroll
            for (int m = 0; m < FM; ++m) {
                int ar = wr * (BM / 2) + m * 16 + lrow;
                af[m] = *reinterpret_cast<const bf16x8*>(&As[ar * 64 + ((lkk ^ (ar & 7)) * 8)]);
            }
#pragma unroll
            for (int n = 0; n < 4; ++n) {
                int br = wc * 64 + n * 16 + lrow;
                bfr[n] = *reinterpret_cast<const bf16x8*>(&Bs[br * 64 + ((lkk ^ (br & 7)) * 8)]);
            }
#pragma unroll
            for (int m = 0; m < FM; ++m)
#pragma unroll
                for (int n = 0; n < 4; ++n)
                    acc[m][n] = __builtin_amdgcn_mfma_f32_16x16x32_bf16(af[m], bfr[n], acc[m][n], 0, 0, 0);
        }
        __syncthreads();
    }

#pragma unroll
    for (int n = 0; n < 4; ++n) {
        int col = col0 + wc * 64 + n * 16 + lrow;
        float bv = bias[col];
#pragma unroll
        for (int m = 0; m < FM; ++m) {
#pragma unroll
            for (int rr = 0; rr < 4; ++rr) {
                int row = row0 + wr * (BM / 2) + m * 16 + lk * 4 + rr;
                float v = acc[m][n][rr] + bv;
                if constexpr (EPI == EPI_XPZ) {
                    if (col < DI) outB[(size_t)row * DI + col] = f2bf(v);
                    else outB2[(size_t)row * DI + (col - DI)] = f2bf(v);
                } else if constexpr (EPI == EPI_COMB) {
                    v += res[(size_t)row * DM + col];
                    outB[(size_t)row * (2 * DM) + col] = f2bf(v);
                } else {
                    outB[(size_t)row * DI + col] = f2bf(softplusf_(v));
                }
            }
        }
    }
}

// ---------------------------------------------------------------------------
// Final fused GEMM: 64x64 tile, dual-B (Wg, Wv), A = combb bf16.
// ---------------------------------------------------------------------------
__global__ __launch_bounds__(256) void gemm_final64(
    const ushort_t* __restrict__ combb,  // [MROWS][2DM] bf16
    const ushort_t* __restrict__ Bg,     // [DM][2DM]
    const ushort_t* __restrict__ Bv,
    const float* __restrict__ bgp, const float* __restrict__ bvp,
    float* __restrict__ out)
{
    __shared__ ushort_t As[64 * 64];
    __shared__ ushort_t Bs1[64 * 64];
    __shared__ ushort_t Bs2[64 * 64];
    int tid = threadIdx.x;
    int lane = tid & 63;
    int w = tid >> 6, wr = w >> 1, wc = w & 1;
    int lrow = lane & 15, lk = lane >> 4;
    int cr = lane >> 3, cs = lane & 7;
    int row0 = blockIdx.y * 64, col0 = blockIdx.x * 64;

    f32x4 accg[2][2], accv[2][2];
#pragma unroll
    for (int m = 0; m < 2; ++m)
#pragma unroll
        for (int n = 0; n < 2; ++n) { accg[m][n] = {0.f,0.f,0.f,0.f}; accv[m][n] = {0.f,0.f,0.f,0.f}; }

    for (int k0 = 0; k0 < 2 * DM; k0 += 64) {
#pragma unroll
        for (int j = 0; j < 6; ++j) {
            int c = j * 4 + w;
            if (c < 8) {
                int r = c * 8 + cr;
                gload16(&combb[(size_t)(row0 + r) * (2 * DM) + k0 + ((cs ^ (r & 7)) * 8)],
                        &As[c * 512]);
            } else if (c < 16) {
                int r = (c - 8) * 8 + cr;
                gload16(&Bg[(size_t)(col0 + r) * (2 * DM) + k0 + ((cs ^ (r & 7)) * 8)],
                        &Bs1[(c - 8) * 512]);
            } else {
                int r = (c - 16) * 8 + cr;
                gload16(&Bv[(size_t)(col0 + r) * (2 * DM) + k0 + ((cs ^ (r & 7)) * 8)],
                        &Bs2[(c - 16) * 512]);
            }
        }
        __syncthreads();
#pragma unroll
        for (int kk = 0; kk < 2; ++kk) {
            int lkk = kk * 4 + lk;
            bf16x8 af[2], b1[2], b2[2];
#pragma unroll
            for (int m = 0; m < 2; ++m) {
                int ar = wr * 32 + m * 16 + lrow;
                af[m] = *reinterpret_cast<const bf16x8*>(&As[ar * 64 + ((lkk ^ (ar & 7)) * 8)]);
            }
#pragma unroll
            for (int n = 0; n < 2; ++n) {
                int br = wc * 32 + n * 16 + lrow;
                b1[n] = *reinterpret_cast<const bf16x8*>(&Bs1[br * 64 + ((lkk ^ (br & 7)) * 8)]);
                b2[n] = *reinterpret_cast<const bf16x8*>(&Bs2[br * 64 + ((lkk ^ (br & 7)) * 8)]);
            }
#pragma unroll
            for (int m = 0; m < 2; ++m)
#pragma unroll
                for (int n = 0; n < 2; ++n) {
                    accg[m][n] = __builtin_amdgcn_mfma_f32_16x16x32_bf16(af[m], b1[n], accg[m][n], 0, 0, 0);
                    accv[m][n] = __builtin_amdgcn_mfma_f32_16x16x32_bf16(af[m], b2[n], accv[m][n], 0, 0, 0);
                }
        }
        __syncthreads();
    }

#pragma unroll
    for (int n = 0; n < 2; ++n) {
        int col = col0 + wc * 32 + n * 16 + lrow;
        float bgv = bgp[col];
        float bvv = bvp[col];
#pragma unroll
        for (int m = 0; m < 2; ++m) {
#pragma unroll
            for (int rr = 0; rr < 4; ++rr) {
                int row = row0 + wr * 32 + m * 16 + lk * 4 + rr;
                float g = sigmoidf_(accg[m][n][rr] + bgv);
                float v = accv[m][n][rr] + bvv;
                float f = bf2f(combb[(size_t)row * (2 * DM) + col]);
                float wv2 = bf2f(combb[(size_t)row * (2 * DM) + DM + col]);
                out[(size_t)row * DM + col] = 0.5f * (g * v + (1.f - g) * (f + wv2));
            }
        }
    }
}

// ---------------------------------------------------------------------------
// Split-K MFMA GEMM for xproj, z-batched.
// ---------------------------------------------------------------------------
__global__ __launch_bounds__(256) void gemm_xproj(
    const ushort_t* __restrict__ A,      // xpcb [2][MROWS][DI]
    const ushort_t* __restrict__ Bt,     // WTxp [2][96][DI]
    float* __restrict__ part)            // [2][NSPLIT][MROWS][96]
{
    int z = blockIdx.z;
    A += (size_t)z * MROWS * DI;
    Bt += (size_t)z * 96 * DI;
    part += (size_t)z * NSPLIT * MROWS * 96;

    __shared__ ushort_t As[128 * LDT];
    __shared__ ushort_t Bs[96 * LDT];
    int tid = threadIdx.x;
    int lane = tid & 63;
    int w = tid >> 6, wr = w >> 1, wc = w & 1;
    int lrow = lane & 15, lk = lane >> 4;
    int s = blockIdx.x, rt = blockIdx.y;
    int row0 = rt * 128;
    int k0 = s * KCH;

    f32x4 acc[4][3];
#pragma unroll
    for (int m = 0; m < 4; ++m)
#pragma unroll
        for (int n = 0; n < 3; ++n) acc[m][n] = {0.f, 0.f, 0.f, 0.f};

    int sr = tid >> 2, ss = tid & 3;
    const ushort_t* ga0 = A + (size_t)(row0 + sr) * DI + k0 + ss * 8;
    const ushort_t* ga1 = A + (size_t)(row0 + sr + 64) * DI + k0 + ss * 8;

    for (int kk = 0; kk < KCH; kk += 32) {
        int4 a0 = *reinterpret_cast<const int4*>(ga0);
        int4 a1 = *reinterpret_cast<const int4*>(ga1);
        ga0 += 32; ga1 += 32;
        __syncthreads();
        *reinterpret_cast<int4*>(&As[sr * LDT + ss * 8]) = a0;
        *reinterpret_cast<int4*>(&As[(sr + 64) * LDT + ss * 8]) = a1;
        for (int i = tid; i < 96 * 4; i += 256) {
            int br = i >> 2, bs = i & 3;
            *reinterpret_cast<int4*>(&Bs[br * LDT + bs * 8]) =
                *reinterpret_cast<const int4*>(&Bt[(size_t)br * DI + k0 + kk + bs * 8]);
        }
        __syncthreads();
        bf16x8 af[4], bfr[3];
#pragma unroll
        for (int m = 0; m < 4; ++m)
            af[m] = *reinterpret_cast<const bf16x8*>(&As[(wr * 64 + m * 16 + lrow) * LDT + lk * 8]);
#pragma unroll
        for (int n = 0; n < 3; ++n)
            bfr[n] = *reinterpret_cast<const bf16x8*>(&Bs[(wc * 48 + n * 16 + lrow) * LDT + lk * 8]);
#pragma unroll
        for (int m = 0; m < 4; ++m)
#pragma unroll
            for (int n = 0; n < 3; ++n)
                acc[m][n] = __builtin_amdgcn_mfma_f32_16x16x32_bf16(af[m], bfr[n], acc[m][n], 0, 0, 0);
    }

#pragma unroll
    for (int n = 0; n < 3; ++n) {
        int col = wc * 48 + n * 16 + lrow;
#pragma unroll
        for (int m = 0; m < 4; ++m) {
#pragma unroll
            for (int rr = 0; rr < 4; ++rr) {
                int row = row0 + wr * 64 + m * 16 + lk * 4 + rr;
                part[((size_t)s * MROWS + row) * 96 + col] = acc[m][n][rr];
            }
        }
    }
}

__global__ __launch_bounds__(256) void dbl_reduce(
    const float* __restrict__ part,   // [2][NSPLIT][MROWS][96]
    float* __restrict__ dblf,         // [2][MROWS][96]
    ushort_t* __restrict__ dtb)       // [2][MROWS][RR]
{
    int idx = blockIdx.x * 256 + threadIdx.x;   // over 2*MROWS*96
    int d = idx / (MROWS * 96);
    int rem = idx - d * (MROWS * 96);
    int row = rem / 96, col = rem - row * 96;
    const float* p = part + (size_t)d * NSPLIT * MROWS * 96;
    float v = 0.f;
#pragma unroll
    for (int s = 0; s < NSPLIT; ++s)
        v += p[((size_t)s * MROWS + row) * 96 + col];
    dblf[idx] = v;
    if (col < RR) dtb[(size_t)d * MROWS * RR + (size_t)row * RR + col] = f2bf(v);
}

// ---------------------------------------------------------------------------
// Depthwise conv K=4 + SiLU, bf16 in/out, direction-batched (blockIdx.y).
// ---------------------------------------------------------------------------
__global__ __launch_bounds__(256) void conv_silu_kernel(
    const ushort_t* __restrict__ xpb,   // [2][MROWS][DI]
    const float* __restrict__ cw,       // [2][DI][4]
    const float* __restrict__ cb,       // [2][DI]
    ushort_t* __restrict__ xpcb)        // [2][MROWS][DI]
{
    int d = blockIdx.y;
    xpb += (size_t)d * MROWS * DI;
    cw += (size_t)d * DI * 4;
    cb += (size_t)d * DI;
    xpcb += (size_t)d * MROWS * DI;
    int idx = blockIdx.x * 256 + threadIdx.x;
    int c = idx & (DI - 1);
    int row = idx >> 11;
    int t = row & (LL - 1);
    int b = row >> 10;
    float w0 = cw[c * 4 + 0], w1 = cw[c * 4 + 1], w2 = cw[c * 4 + 2], w3 = cw[c * 4 + 3];
    float acc = cb[c];
    if (!d) {
#pragma unroll
        for (int k = 0; k < 4; ++k) {
            int tt = t - 3 + k;
            if (tt >= 0) {
                float wv = (k == 0) ? w0 : (k == 1) ? w1 : (k == 2) ? w2 : w3;
                acc = fmaf(wv, bf2f(xpb[(size_t)(b * LL + tt) * DI + c]), acc);
            }
        }
    } else {
#pragma unroll
        for (int k = 0; k < 4; ++k) {
            int tt = t + 3 - k;
            if (tt < LL) {
                float wv = (k == 0) ? w0 : (k == 1) ? w1 : (k == 2) ? w2 : w3;
                acc = fmaf(wv, bf2f(xpb[(size_t)(b * LL + tt) * DI + c]), acc);
            }
        }
    }
    xpcb[idx] = f2bf(siluf_(acc));
}

// ---------------------------------------------------------------------------
// Chunked scan (direction+batch in blockIdx.z: z = d*BB + b)
// ---------------------------------------------------------------------------
__global__ __launch_bounds__(256) void scan_part1(
    const ushort_t* __restrict__ deltab,  // [2][MROWS][DI]
    const ushort_t* __restrict__ xpcb,    // [2][MROWS][DI]
    const float* __restrict__ dblf,       // [2][MROWS][96]
    const float* __restrict__ A_log,      // [2][DI][NS]
    float* __restrict__ chunkS,           // [2][BB][NCH][DI]
    ushort_t* __restrict__ chunkH)        // [2][BB][NCH][DI][NS]
{
    int zz = blockIdx.z;
    int d = zz >> 1, b = zz & 1;
    const ushort_t* delta_d = deltab + (size_t)d * MROWS * DI;
    const ushort_t* xpc_d = xpcb + (size_t)d * MROWS * DI;
    const float* dbl_d = dblf + (size_t)d * MROWS * 96;
    const float* Alg = A_log + (size_t)d * DI * NS;
    int reverse = d;

    int c = blockIdx.x * 256 + threadIdx.x;
    int ch = blockIdx.y;
    int base = b * LL;

    __shared__ float sB[CLEN][16];
    for (int r = threadIdx.x >> 4; r < CLEN; r += 16) {
        int col = threadIdx.x & 15;
        int i = ch * CLEN + r;
        int t = reverse ? (LL - 1 - i) : i;
        sB[r][col] = dbl_d[(size_t)(base + t) * 96 + RR + col];
    }
    __syncthreads();

    float Ac[NS];
#pragma unroll
    for (int q = 0; q < 4; ++q) {
        float4 a = *reinterpret_cast<const float4*>(&Alg[(size_t)c * NS + q * 4]);
        Ac[q * 4 + 0] = -__expf(a.x);
        Ac[q * 4 + 1] = -__expf(a.y);
        Ac[q * 4 + 2] = -__expf(a.z);
        Ac[q * 4 + 3] = -__expf(a.w);
    }
    float h[NS] = {};
    float S = 0.f;
    for (int ii = 0; ii < CLEN; ++ii) {
        int i = ch * CLEN + ii;
        int t = reverse ? (LL - 1 - i) : i;
        size_t row = (size_t)(base + t);
        float dlt = bf2f(delta_d[row * DI + c]);
        float xv = bf2f(xpc_d[row * DI + c]);
        S += dlt;
        float dx = dlt * xv;
        float4 B0 = *reinterpret_cast<const float4*>(&sB[ii][0]);
        float4 B1 = *reinterpret_cast<const float4*>(&sB[ii][4]);
        float4 B2 = *reinterpret_cast<const float4*>(&sB[ii][8]);
        float4 B3 = *reinterpret_cast<const float4*>(&sB[ii][12]);
        float Bv[NS] = {B0.x, B0.y, B0.z, B0.w, B1.x, B1.y, B1.z, B1.w,
                        B2.x, B2.y, B2.z, B2.w, B3.x, B3.y, B3.z, B3.w};
#pragma unroll
        for (int n = 0; n < NS; ++n)
            h[n] = fmaf(__expf(dlt * Ac[n]), h[n], dx * Bv[n]);
    }
    size_t sidx = ((size_t)((d * BB + b) * NCH + ch)) * DI + c;
    chunkS[sidx] = S;
    ushort_t o[16];
#pragma unroll
    for (int n = 0; n < NS; ++n) o[n] = f2bf(h[n]);
    ushort_t* hp = chunkH + sidx * NS;
    *reinterpret_cast<int4*>(&hp[0]) = *reinterpret_cast<int4*>(&o[0]);
    *reinterpret_cast<int4*>(&hp[8]) = *reinterpret_cast<int4*>(&o[8]);
}

__global__ __launch_bounds__(256) void scan_part2(
    ushort_t* __restrict__ chunkH,
    const float* __restrict__ chunkS,
    const float* __restrict__ A_log)
{
    int idx = blockIdx.x * 256 + threadIdx.x;   // over 2*BB*DI*NS
    int d = idx >> 16;
    int r = idx & 65535;
    int n = r & 15;
    int c = (r >> 4) & (DI - 1);
    int b = r >> 15;
    float Ac = -__expf(A_log[(size_t)d * DI * NS + (size_t)c * NS + n]);
    float cur = 0.f;
    for (int j = 0; j < NCH; ++j) {
        size_t sidx = ((size_t)((d * BB + b) * NCH + j)) * DI + c;
        float S = chunkS[sidx];
        float hf = bf2f(chunkH[sidx * NS + n]);
        float nxt = fmaf(__expf(Ac * S), cur, hf);
        chunkH[sidx * NS + n] = f2bf(cur);
        cur = nxt;
    }
}

__global__ __launch_bounds__(256) void scan_part3(
    const ushort_t* __restrict__ deltab,
    const ushort_t* __restrict__ xpcb,
    const float* __restrict__ dblf,
    const ushort_t* __restrict__ zbuf,    // [2][MROWS][DI]
    const float* __restrict__ A_log,
    const float* __restrict__ Dp,         // [2][DI]
    const ushort_t* __restrict__ chunkH,
    ushort_t* __restrict__ ybufb)         // [2][MROWS][DI]
{
    int zz = blockIdx.z;
    int d = zz >> 1, b = zz & 1;
    const ushort_t* delta_d = deltab + (size_t)d * MROWS * DI;
    const ushort_t* xpc_d = xpcb + (size_t)d * MROWS * DI;
    const float* dbl_d = dblf + (size_t)d * MROWS * 96;
    const ushort_t* z_d = zbuf + (size_t)d * MROWS * DI;
    const float* Alg = A_log + (size_t)d * DI * NS;
    const float* Dp_d = Dp + (size_t)d * DI;
    ushort_t* y_d = ybufb + (size_t)d * MROWS * DI;
    int reverse = d;

    int c = blockIdx.x * 256 + threadIdx.x;
    int ch = blockIdx.y;
    int base = b * LL;

    __shared__ float sBC[CLEN][32];
    for (int r = threadIdx.x >> 5; r < CLEN; r += 8) {
        int col = threadIdx.x & 31;
        int i = ch * CLEN + r;
        int t = reverse ? (LL - 1 - i) : i;
        sBC[r][col] = dbl_d[(size_t)(base + t) * 96 + RR + col];
    }
    __syncthreads();

    float Ac[NS];
#pragma unroll
    for (int q = 0; q < 4; ++q) {
        float4 a = *reinterpret_cast<const float4*>(&Alg[(size_t)c * NS + q * 4]);
        Ac[q * 4 + 0] = -__expf(a.x);
        Ac[q * 4 + 1] = -__expf(a.y);
        Ac[q * 4 + 2] = -__expf(a.z);
        Ac[q * 4 + 3] = -__expf(a.w);
    }
    size_t sidx = ((size_t)((d * BB + b) * NCH + ch)) * DI + c;
    const ushort_t* hp = chunkH + sidx * NS;
    int4 h0 = *reinterpret_cast<const int4*>(&hp[0]);
    int4 h1 = *reinterpret_cast<const int4*>(&hp[8]);
    const ushort_t* hs0 = reinterpret_cast<const ushort_t*>(&h0);
    const ushort_t* hs1 = reinterpret_cast<const ushort_t*>(&h1);
    float h[NS];
#pragma unroll
    for (int n = 0; n < 8; ++n) { h[n] = bf2f(hs0[n]); h[8 + n] = bf2f(hs1[n]); }
    float Dc = Dp_d[c];
    for (int ii = 0; ii < CLEN; ++ii) {
        int i = ch * CLEN + ii;
        int t = reverse ? (LL - 1 - i) : i;
        size_t row = (size_t)(base + t);
        float dlt = bf2f(delta_d[row * DI + c]);
        float xv = bf2f(xpc_d[row * DI + c]);
        float dx = dlt * xv;
        float4 B0 = *reinterpret_cast<const float4*>(&sBC[ii][0]);
        float4 B1 = *reinterpret_cast<const float4*>(&sBC[ii][4]);
        float4 B2 = *reinterpret_cast<const float4*>(&sBC[ii][8]);
        float4 B3 = *reinterpret_cast<const float4*>(&sBC[ii][12]);
        float4 C0 = *reinterpret_cast<const float4*>(&sBC[ii][16]);
        float4 C1 = *reinterpret_cast<const float4*>(&sBC[ii][20]);
        float4 C2 = *reinterpret_cast<const float4*>(&sBC[ii][24]);
        float4 C3 = *reinterpret_cast<const float4*>(&sBC[ii][28]);
        float Bv[NS] = {B0.x, B0.y, B0.z, B0.w, B1.x, B1.y, B1.z, B1.w,
                        B2.x, B2.y, B2.z, B2.w, B3.x, B3.y, B3.z, B3.w};
        float Cv[NS] = {C0.x, C0.y, C0.z, C0.w, C1.x, C1.y, C1.z, C1.w,
                        C2.x, C2.y, C2.z, C2.w, C3.x, C3.y, C3.z, C3.w};
        float y = 0.f;
#pragma unroll
        for (int n = 0; n < NS; ++n) {
            h[n] = fmaf(__expf(dlt * Ac[n]), h[n], dx * Bv[n]);
            y = fmaf(h[n], Cv[n], y);
        }
        float z = bf2f(z_d[row * DI + c]);
        y_d[row * DI + c] = f2bf((y + xv * Dc) * siluf_(z));
    }
}

// ---------------------------------------------------------------------------
extern "C" void kernel_launch(void* const* d_in, const int* in_sizes, int n_in,
                              void* d_out, int out_size, void* d_ws, size_t ws_size,
                              hipStream_t stream)
{
    const float* x      = (const float*)d_in[0];
    const float* ln_w   = (const float*)d_in[1];
    const float* ln_b   = (const float*)d_in[2];
    const float* W_in   = (const float*)d_in[3];
    const float* b_in   = (const float*)d_in[4];
    const float* conv_w = (const float*)d_in[5];
    const float* conv_b = (const float*)d_in[6];
    const float* W_xproj= (const float*)d_in[7];
    const float* W_dt   = (const float*)d_in[8];
    const float* b_dt   = (const float*)d_in[9];
    const float* A_log  = (const float*)d_in[10];
    const float* Dp     = (const float*)d_in[11];
    const float* W_out  = (const float*)d_in[12];
    const float* b_out  = (const float*)d_in[13];
    const float* Wg     = (const float*)d_in[14];
    const float* bg     = (const float*)d_in[15];
    const float* Wv     = (const float*)d_in[16];
    const float* bv     = (const float*)d_in[17];
    float* out = (float*)d_out;

    // ---- workspace (~127 MB, lifetime-aliased) ----
    ushort_t* sb = (ushort_t*)d_ws;
    size_t o = 0;
    // R0: xlnb[2] + xpb[2]; later aliased by part (fp32 split-K) then ybufb[2]
    ushort_t* R0 = sb + o;
    ushort_t* xlnb = R0;                                   // 2*MROWS*DM sh
    ushort_t* xpb  = R0 + (size_t)2 * MROWS * DM;          // 2*MROWS*DI sh
    o += (size_t)2 * MROWS * DM + (size_t)2 * MROWS * DI;  // 12.58M sh
    float* part = (float*)R0;        // [2][NSPLIT][MROWS][96] = 25.17 MB (exact fit)
    ushort_t* ybufb = R0;            // [2][MROWS][DI] (alias, after reduce)
    ushort_t* zb     = sb + o; o += (size_t)2 * MROWS * DI;
    ushort_t* xpcb   = sb + o; o += (size_t)2 * MROWS * DI;
    ushort_t* deltab = sb + o; o += (size_t)2 * MROWS * DI;
    ushort_t* chHb   = sb + o; o += (size_t)2 * BB * NCH * DI * NS;   // 4.19M sh
    ushort_t* combb  = sb + o; o += (size_t)MROWS * 2 * DM;           // 4.19M sh
    // dblf/dtb/chS live inside combb's region (dead until COMB writes it)
    float* dblf = (float*)combb;                                      // 2*MROWS*96 f
    ushort_t* dtb = combb + (size_t)2 * (2 * MROWS * 96);             // 2*MROWS*RR sh
    float* chS = (float*)(combb + (size_t)2 * (2 * MROWS * 96) + (size_t)2 * MROWS * RR);
    ushort_t* WTin   = sb + o; o += (size_t)2 * (2 * DI) * DM;
    ushort_t* WTout  = sb + o; o += (size_t)2 * DM * DI;
    ushort_t* WTgv   = sb + o; o += (size_t)2 * DM * (2 * DM);
    ushort_t* WTxp   = sb + o; o += (size_t)2 * 96 * DI;
    ushort_t* WTdt   = sb + o; o += (size_t)2 * DI * RR;

    // ---- weight transforms ----
    tcast<<<dim3(DM / 64, DI / 64, 2), 256, 0, stream>>>(
        W_out, (long)DI * DM, WTout, (long)DM * DI, DI, DM);
    tcast<<<dim3(DM / 64, (2 * DM) / 64, 1), 256, 0, stream>>>(
        Wg, 0, WTgv, 0, 2 * DM, DM);
    tcast<<<dim3(DM / 64, (2 * DM) / 64, 1), 256, 0, stream>>>(
        Wv, 0, WTgv + (size_t)DM * 2 * DM, 0, 2 * DM, DM);
    tcast<<<dim3(DI / 64, RR / 64, 2), 256, 0, stream>>>(
        W_dt, (long)RR * DI, WTdt, (long)DI * RR, RR, DI);
    tcastP<<<dim3((DI * 96 + 255) / 256, 1, 2), 256, 0, stream>>>(
        W_xproj, (long)DI * 96, WTxp, (long)96 * DI, DI, 96);
    tcast<<<dim3((2 * DI) / 64, DM / 64, 2), 256, 0, stream>>>(
        W_in, (long)DM * 2 * DI, WTin, (long)(2 * DI) * DM, DM, 2 * DI);

    // ---- both-direction pipeline (batched) ----
    ln_kernel<<<MROWS, 256, 0, stream>>>(x, ln_w, ln_b, xlnb);

    // xz = xln @ W_in + b_in -> xpb | zb   (z = direction)
    gemm_as<128, EPI_XPZ><<<dim3((2 * DI) / 128, MROWS / 128, 2), 256, 0, stream>>>(
        xlnb, DM, (long)MROWS * DM, WTin, DM, (long)(2 * DI) * DM,
        b_in, 2 * DI, xpb, (long)MROWS * DI, zb, (long)MROWS * DI, nullptr, DM);

    conv_silu_kernel<<<dim3((MROWS * DI) / 256, 2), 256, 0, stream>>>(
        xpb, conv_w, conv_b, xpcb);

    // dbl = xpc @ W_xproj (split-K + reduce), both directions
    gemm_xproj<<<dim3(NSPLIT, MROWS / 128, 2), 256, 0, stream>>>(xpcb, WTxp, part);
    dbl_reduce<<<(2 * MROWS * 96) / 256, 256, 0, stream>>>(part, dblf, dtb);

    // delta = softplus(dt @ W_dt + b_dt) -> bf16
    gemm_as<128, EPI_SOFT><<<dim3(DI / 128, MROWS / 128, 2), 256, 0, stream>>>(
        dtb, RR, (long)MROWS * RR, WTdt, RR, (long)DI * RR,
        b_dt, DI, deltab, (long)MROWS * DI, nullptr, 0, nullptr, RR);

    // chunked scan (both directions, both batches)
    scan_part1<<<dim3(DI / 256, NCH, 4), 256, 0, stream>>>(
        deltab, xpcb, dblf, A_log, chS, chHb);
    scan_part2<<<(2 * BB * DI * NS) / 256, 256, 0, stream>>>(chHb, chS, A_log);
    scan_part3<<<dim3(DI / 256, NCH, 4), 256, 0, stream>>>(
        deltab, xpcb, dblf, zb, A_log, Dp, chHb, ybufb);

    // comb[:, z*DM:] = x + ybuf[z] @ W_out[z] + b_out[z]  (bf16 out)
    gemm_as<64, EPI_COMB><<<dim3(DM / 128, MROWS / 64, 2), 256, 0, stream>>>(
        ybufb, DI, (long)MROWS * DI, WTout, DI, (long)DM * DI,
        b_out, DM, combb, DM, nullptr, 0, x, DI);

    // final fused dual GEMM + sigmoid mix
    gemm_final64<<<dim3(DM / 64, MROWS / 64), 256, 0, stream>>>(
        combb, WTgv, WTgv + (size_t)DM * 2 * DM, bg, bv, out);
}